// Round 2
// baseline (4310.459 us; speedup 1.0000x reference)
//
#include <hip/hip_runtime.h>
#include <math.h>
#include <stdint.h>

// tokens: L=160, Bcols=320 (chunked by bb: W=160 or 320 per chunk), E=256
// token local index t' = l*W + lb*160 + (spatial col), lb = bb - bb0

// ---------------------------------------------------------------------------
// gather pass1: x0[t'][cc] = src[bb][cc][u*5+v][y][x], l=u*32+y, col=lb*160+v*32+x
// grid (128, 25, NBB): bx = cct + 4*y ; by = n = u*5+v ; bz = lb
__global__ __launch_bounds__(256) void gather1(const float* __restrict__ src, float* __restrict__ x0,
                                               int W, int bb0) {
    int cct = blockIdx.x & 3, y = blockIdx.x >> 2;
    int n = blockIdx.y; int u = n / 5, v = n % 5;
    int lb = blockIdx.z, bb = bb0 + lb;
    __shared__ float tile[32][33];
    int tx = threadIdx.x & 31, tg = threadIdx.x >> 5;
    const float* s = src + (((size_t)(bb * 128 + cct * 32) * 25 + n) * 32 + y) * 32;
    #pragma unroll
    for (int i = 0; i < 4; i++) {
        int cl = tg + 8 * i;
        tile[cl][tx] = s[(size_t)cl * 25600 + tx];      // [cc_local][x]
    }
    __syncthreads();
    float* d = x0 + ((size_t)(u * 32 + y) * W + lb * 160 + v * 32) * 128 + cct * 32;
    #pragma unroll
    for (int i = 0; i < 4; i++) {
        int xx = tg + 8 * i;
        d[(size_t)xx * 128 + tx] = tile[tx][xx];
    }
}

// gather pass2: x0[t'][cc] = src[bb][cc][u*5+v][y][x], l=v*32+x, col=lb*160+u*32+y
__global__ __launch_bounds__(256) void gather2(const float* __restrict__ src, float* __restrict__ x0,
                                               int W, int bb0) {
    int cct = blockIdx.x & 3, x = blockIdx.x >> 2;
    int n = blockIdx.y; int u = n / 5, v = n % 5;
    int lb = blockIdx.z, bb = bb0 + lb;
    __shared__ float tile[32][33];
    int tx = threadIdx.x & 31, tg = threadIdx.x >> 5;
    const float* s = src + (((size_t)(bb * 128 + cct * 32) * 25 + n) * 32) * 32 + x;
    #pragma unroll
    for (int i = 0; i < 4; i++) {
        int cl = tg + 8 * i;
        tile[cl][tx] = s[(size_t)cl * 25600 + tx * 32];  // [cc_local][y]
    }
    __syncthreads();
    float* d = x0 + ((size_t)(v * 32 + x) * W + lb * 160 + u * 32) * 128 + cct * 32;
    #pragma unroll
    for (int i = 0; i < 4; i++) {
        int yy = tg + 8 * i;
        d[(size_t)yy * 128 + tx] = tile[tx][yy];
    }
}

// scatter pass1: xs[lb][cc][u*5+v][y][x] = ot[(u*32+y)*W + lb*160 + v*32+x][cc]
__global__ __launch_bounds__(256) void scatter1(const float* __restrict__ ot, float* __restrict__ xs,
                                                int W) {
    int cct = blockIdx.x & 3, y = blockIdx.x >> 2;
    int n = blockIdx.y; int u = n / 5, v = n % 5;
    int lb = blockIdx.z;
    __shared__ float tile[32][33];
    int tx = threadIdx.x & 31, tg = threadIdx.x >> 5;
    const float* s = ot + ((size_t)(u * 32 + y) * W + lb * 160 + v * 32) * 128 + cct * 32;
    #pragma unroll
    for (int i = 0; i < 4; i++) {
        int xx = tg + 8 * i;
        tile[xx][tx] = s[(size_t)xx * 128 + tx];         // [x][cc_local]
    }
    __syncthreads();
    float* d = xs + (((size_t)(lb * 128 + cct * 32) * 25 + n) * 32 + y) * 32;
    #pragma unroll
    for (int i = 0; i < 4; i++) {
        int cl = tg + 8 * i;
        d[(size_t)cl * 25600 + tx] = tile[tx][cl];
    }
}

// scatter pass2: xs[lb][cc][u*5+v][y][x] = ot[(v*32+x)*W + lb*160 + u*32+y][cc]
__global__ __launch_bounds__(256) void scatter2(const float* __restrict__ ot, float* __restrict__ xs,
                                                int W) {
    int cct = blockIdx.x & 3, y = blockIdx.x >> 2;
    int n = blockIdx.y; int u = n / 5, v = n % 5;
    int lb = blockIdx.z;
    __shared__ float tile[32][33];
    int tx = threadIdx.x & 31, tg = threadIdx.x >> 5;
    const float* s = ot + ((size_t)(lb * 160 + u * 32 + y)) * 128 + cct * 32;
    #pragma unroll
    for (int i = 0; i < 4; i++) {
        int xx = tg + 8 * i;
        tile[xx][tx] = s[(size_t)(v * 32 + xx) * W * 128 + tx];
    }
    __syncthreads();
    float* d = xs + (((size_t)(lb * 128 + cct * 32) * 25 + n) * 32 + y) * 32;
    #pragma unroll
    for (int i = 0; i < 4; i++) {
        int cl = tg + 8 * i;
        d[(size_t)cl * 25600 + tx] = tile[tx][cl];
    }
}

// ---------------------------------------------------------------------------
// LayerNorm over E=256, one wave per token, 4 tokens per block
__global__ __launch_bounds__(256) void ln_kernel(const float* __restrict__ in, float* __restrict__ out,
                                                 const float* __restrict__ w, const float* __restrict__ b) {
    int tok = blockIdx.x * 4 + (threadIdx.x >> 6);
    int lane = threadIdx.x & 63;
    const float4 v4 = ((const float4*)(in + (size_t)tok * 256))[lane];
    float s = v4.x + v4.y + v4.z + v4.w;
    #pragma unroll
    for (int off = 32; off > 0; off >>= 1) s += __shfl_xor(s, off);
    float mu = s * (1.0f / 256.0f);
    float dx = v4.x - mu, dy = v4.y - mu, dz = v4.z - mu, dw = v4.w - mu;
    float vs = dx * dx + dy * dy + dz * dz + dw * dw;
    #pragma unroll
    for (int off = 32; off > 0; off >>= 1) vs += __shfl_xor(vs, off);
    float inv = rsqrtf(vs * (1.0f / 256.0f) + 1e-5f);
    float4 wv = ((const float4*)w)[lane];
    float4 bv = ((const float4*)b)[lane];
    float4 o4;
    o4.x = dx * inv * wv.x + bv.x;
    o4.y = dy * inv * wv.y + bv.y;
    o4.z = dz * inv * wv.z + bv.z;
    o4.w = dw * inv * wv.w + bv.w;
    ((float4*)(out + (size_t)tok * 256))[lane] = o4;
}

// ---------------------------------------------------------------------------
// fp32 GEMM: Y[M,N] = X[M,K] @ Wt[N,K]^T (+R) (relu?)  tiles 128x128x16
__global__ __launch_bounds__(256) void gemm_f32(const float* __restrict__ X, const float* __restrict__ Wt,
                                                float* Y, const float* R, int N, int K, int relu) {
    __shared__ float Xs[16][132];
    __shared__ float Ws[16][132];
    const int bm = blockIdx.x * 128, bn = blockIdx.y * 128;
    const int tid = threadIdx.x;
    const int kcol = tid & 15, rbase = tid >> 4;
    const int tm = (tid & 15) * 8, tn = (tid >> 4) * 8;
    float acc[8][8] = {};
    for (int k0 = 0; k0 < K; k0 += 16) {
        #pragma unroll
        for (int i = 0; i < 8; i++) {
            int row = rbase + i * 16;
            Xs[kcol][row] = X[(size_t)(bm + row) * K + k0 + kcol];
            Ws[kcol][row] = Wt[(size_t)(bn + row) * K + k0 + kcol];
        }
        __syncthreads();
        #pragma unroll
        for (int kk = 0; kk < 16; kk++) {
            float xr[8], wr[8];
            #pragma unroll
            for (int i = 0; i < 8; i++) xr[i] = Xs[kk][tm + i];
            #pragma unroll
            for (int j = 0; j < 8; j++) wr[j] = Ws[kk][tn + j];
            #pragma unroll
            for (int i = 0; i < 8; i++)
                #pragma unroll
                for (int j = 0; j < 8; j++)
                    acc[i][j] = fmaf(xr[i], wr[j], acc[i][j]);
        }
        __syncthreads();
    }
    #pragma unroll
    for (int i = 0; i < 8; i++) {
        size_t rowoff = (size_t)(bm + tm + i) * N + bn + tn;
        #pragma unroll
        for (int j = 0; j < 8; j++) {
            float val = acc[i][j];
            if (R) val += R[rowoff + j];
            if (relu) val = fmaxf(val, 0.0f);
            Y[rowoff + j] = val;
        }
    }
}

// ---------------------------------------------------------------------------
// Attention: one block per (col, head). L=160, hd=32. Banded mask:
// query (uq,yq) attends keys (uk, yk) for all uk, yk in [yq-5, yq+5].
__global__ __launch_bounds__(256) void attn_kernel(const float* __restrict__ qk,
                                                   const float* __restrict__ v,
                                                   float* __restrict__ o, int W) {
    const int bidx = blockIdx.x >> 3;
    const int h = blockIdx.x & 7;
    __shared__ float ks[160][36], vs[160][36];
    const int tid = threadIdx.x;
    for (int idx = tid; idx < 160 * 32; idx += 256) {
        int l = idx >> 5, d = idx & 31;
        size_t base = (size_t)l * W + bidx;
        ks[l][d] = qk[base * 512 + 256 + h * 32 + d];
        vs[l][d] = v[base * 256 + h * 32 + d];
    }
    __syncthreads();
    if (tid >= 160) return;
    const int yq = tid & 31;
    float4 qr[8];
    {
        const float4* qp = (const float4*)(qk + ((size_t)tid * W + bidx) * 512 + h * 32);
        #pragma unroll
        for (int i = 0; i < 8; i++) qr[i] = qp[i];
    }
    float s[5][11];
    float mx = -1e30f;
    #pragma unroll
    for (int uk = 0; uk < 5; uk++) {
        #pragma unroll
        for (int t = 0; t < 11; t++) {
            int yk = yq - 5 + t;
            float sc = -1e30f;
            if ((unsigned)yk < 32u) {
                const float4* kp = (const float4*)(&ks[uk * 32 + yk][0]);
                float d0 = 0.0f;
                #pragma unroll
                for (int i = 0; i < 8; i++) {
                    float4 kv = kp[i];
                    d0 = fmaf(qr[i].x, kv.x, d0);
                    d0 = fmaf(qr[i].y, kv.y, d0);
                    d0 = fmaf(qr[i].z, kv.z, d0);
                    d0 = fmaf(qr[i].w, kv.w, d0);
                }
                sc = d0 * 0.17677669529663687f;  // 1/sqrt(32)
            }
            s[uk][t] = sc;
            mx = fmaxf(mx, sc);
        }
    }
    float sum = 0.0f;
    float4 oa[8] = {};
    #pragma unroll
    for (int uk = 0; uk < 5; uk++) {
        #pragma unroll
        for (int t = 0; t < 11; t++) {
            int yk = yq - 5 + t;
            if ((unsigned)yk < 32u) {
                float p = __expf(s[uk][t] - mx);
                sum += p;
                const float4* vp = (const float4*)(&vs[uk * 32 + yk][0]);
                #pragma unroll
                for (int i = 0; i < 8; i++) {
                    float4 vv4 = vp[i];
                    oa[i].x = fmaf(p, vv4.x, oa[i].x);
                    oa[i].y = fmaf(p, vv4.y, oa[i].y);
                    oa[i].z = fmaf(p, vv4.z, oa[i].z);
                    oa[i].w = fmaf(p, vv4.w, oa[i].w);
                }
            }
        }
    }
    float inv = 1.0f / sum;
    float* op = o + ((size_t)tid * W + bidx) * 256 + h * 32;
    #pragma unroll
    for (int i = 0; i < 8; i++) {
        op[i * 4 + 0] = oa[i].x * inv;
        op[i * 4 + 1] = oa[i].y * inv;
        op[i * 4 + 2] = oa[i].z * inv;
        op[i * 4 + 3] = oa[i].w * inv;
    }
}

// ---------------------------------------------------------------------------
// 3x3 conv (per depth slice), 128->128 ch, pad 1, + residual.
// grid (NBB*25, 16). Input xs is chunk-local [lb][128][25][32][32];
// res/out indexed with global bb = bb0 + lb. In-place res==out is safe.
__global__ __launch_bounds__(256) void conv_kernel(const float* __restrict__ in,
                                                   const float* __restrict__ wgt,
                                                   const float* __restrict__ res,
                                                   float* __restrict__ out, int bb0) {
    const int slice = blockIdx.x;
    const int lb = slice / 25, n = slice % 25;
    const int bb = bb0 + lb;
    const int cot = blockIdx.y;
    __shared__ float ins[8][34][34];
    const int tid = threadIdx.x;
    const int tx = tid & 31, yg = tid >> 5;
    float acc[8][4] = {};
    const float* inbase = in + ((size_t)lb * 128 * 25 + n) * 1024;
    for (int ci0 = 0; ci0 < 128; ci0 += 8) {
        for (int idx = tid; idx < 8 * 34 * 34; idx += 256) {
            int ci = idx / 1156, rem = idx % 1156;
            int yy = rem / 34, xx = rem % 34;
            int gy = yy - 1, gx = xx - 1;
            float val = 0.0f;
            if (gy >= 0 && gy < 32 && gx >= 0 && gx < 32)
                val = inbase[(size_t)(ci0 + ci) * 25600 + gy * 32 + gx];
            ins[ci][yy][xx] = val;
        }
        __syncthreads();
        #pragma unroll
        for (int ci = 0; ci < 8; ci++) {
            float pix[6][3];
            #pragma unroll
            for (int r = 0; r < 6; r++)
                #pragma unroll
                for (int c = 0; c < 3; c++)
                    pix[r][c] = ins[ci][yg * 4 + r][tx + c];
            #pragma unroll
            for (int co = 0; co < 8; co++) {
                const float* wp = wgt + ((size_t)(cot * 8 + co) * 128 + ci0 + ci) * 9;
                float w0 = wp[0], w1 = wp[1], w2 = wp[2];
                float w3 = wp[3], w4 = wp[4], w5 = wp[5];
                float w6 = wp[6], w7 = wp[7], w8 = wp[8];
                #pragma unroll
                for (int yy = 0; yy < 4; yy++) {
                    float a = acc[co][yy];
                    a = fmaf(pix[yy + 0][0], w0, a);
                    a = fmaf(pix[yy + 0][1], w1, a);
                    a = fmaf(pix[yy + 0][2], w2, a);
                    a = fmaf(pix[yy + 1][0], w3, a);
                    a = fmaf(pix[yy + 1][1], w4, a);
                    a = fmaf(pix[yy + 1][2], w5, a);
                    a = fmaf(pix[yy + 2][0], w6, a);
                    a = fmaf(pix[yy + 2][1], w7, a);
                    a = fmaf(pix[yy + 2][2], w8, a);
                    acc[co][yy] = a;
                }
            }
        }
        __syncthreads();
    }
    #pragma unroll
    for (int co = 0; co < 8; co++) {
        #pragma unroll
        for (int yy = 0; yy < 4; yy++) {
            size_t off = (((size_t)(bb * 128 + cot * 8 + co) * 25 + n) * 32 + (yg * 4 + yy)) * 32 + tx;
            out[off] = acc[co][yy] + res[off];
        }
    }
}

// ---------------------------------------------------------------------------
extern "C" void kernel_launch(void* const* d_in, const int* in_sizes, int n_in,
                              void* d_out, int out_size, void* d_ws, size_t ws_size,
                              hipStream_t stream) {
    (void)in_sizes; (void)n_in; (void)out_size;
    const float* buffer     = (const float*)d_in[0];
    const float* Win        = (const float*)d_in[1];
    const float* ln_w       = (const float*)d_in[2];
    const float* ln_b       = (const float*)d_in[3];
    const float* in_proj    = (const float*)d_in[4];
    const float* attn_out_w = (const float*)d_in[5];
    const float* ffn_ln_w   = (const float*)d_in[6];
    const float* ffn_ln_b   = (const float*)d_in[7];
    const float* ff1        = (const float*)d_in[8];
    const float* ff2        = (const float*)d_in[9];
    const float* Wout       = (const float*)d_in[10];
    const float* conv_w     = (const float*)d_in[11];
    float* out = (float*)d_out;
    float* ws  = (float*)d_ws;

    // Chunking over bb: NBB batch items per chunk. Scratch = T*1408 floats,
    // T = NBB*25600.  NBB=2 -> 288.4 MB, NBB=1 -> 144.2 MB.
    int NBB = (ws_size >= (size_t)2 * 25600 * 1408 * 4) ? 2 : 1;
    const int W = NBB * 160;          // b-columns per chunk
    const size_t T = (size_t)NBB * 25600;

    // workspace layout (floats), per chunk (reused across chunks)
    float* x0  = ws;                  // T*128  (gather out / final token out E)
    float* A   = ws + T * 128;        // T*256  tok (residual stream)
    float* B   = ws + T * 384;        // T*256  tn / vv / tn2
    float* C   = ws + T * 640;        // T*512  qk / ffn hidden / scatter buf
    float* D   = ws + T * 1152;       // T*256  attn out
    // end at T*1408

    const int GM = (int)(T / 128);    // gemm grid.x (200 or 400)

    for (int pass = 0; pass < 2; pass++) {
        const float* src = (pass == 0) ? buffer : out;   // pass1 result lives in d_out
        for (int bb0 = 0; bb0 < 2; bb0 += NBB) {
            if (pass == 0) gather1<<<dim3(128, 25, NBB), 256, 0, stream>>>(src, x0, W, bb0);
            else           gather2<<<dim3(128, 25, NBB), 256, 0, stream>>>(src, x0, W, bb0);

            // tok = x0 @ Win^T                  (K=128 -> N=256)
            gemm_f32<<<dim3(GM, 2), 256, 0, stream>>>(x0, Win, A, nullptr, 256, 128, 0);
            // tn = LN(tok)
            ln_kernel<<<(int)(T / 4), 256, 0, stream>>>(A, B, ln_w, ln_b);
            // qk = tn @ [Wq;Wk]^T               (N=512)
            gemm_f32<<<dim3(GM, 4), 256, 0, stream>>>(B, in_proj, C, nullptr, 512, 256, 0);
            // vv = tok @ Wv^T (un-normed tok) -> overwrite B
            gemm_f32<<<dim3(GM, 2), 256, 0, stream>>>(A, in_proj + (size_t)512 * 256, B, nullptr, 256, 256, 0);
            // attention
            attn_kernel<<<W * 8, 256, 0, stream>>>(C, B, D, W);
            // tok = ob @ attn_out_w^T + tok  (in-place residual on A)
            gemm_f32<<<dim3(GM, 2), 256, 0, stream>>>(D, attn_out_w, A, A, 256, 256, 0);
            // tn2 = LN_ffn(tok)
            ln_kernel<<<(int)(T / 4), 256, 0, stream>>>(A, B, ffn_ln_w, ffn_ln_b);
            // hidden = relu(tn2 @ ff1^T)        (N=512)
            gemm_f32<<<dim3(GM, 4), 256, 0, stream>>>(B, ff1, C, nullptr, 512, 256, 1);
            // tok = hidden @ ff2^T + tok        (K=512)
            gemm_f32<<<dim3(GM, 2), 256, 0, stream>>>(C, ff2, A, A, 256, 512, 0);
            // ot = tok @ Wout^T                 (N=128) -> x0 region (free now)
            gemm_f32<<<dim3(GM, 1), 256, 0, stream>>>(A, Wout, x0, nullptr, 128, 256, 0);

            // scatter token-major -> image layout, into C region (free now)
            if (pass == 0) scatter1<<<dim3(128, 25, NBB), 256, 0, stream>>>(x0, C, W);
            else           scatter2<<<dim3(128, 25, NBB), 256, 0, stream>>>(x0, C, W);

            // conv + residual.  pass0: res=buffer, dst=d_out (holds sc2).
            // pass1: res=d_out (sc2), dst=d_out in-place (per-element, race-free).
            conv_kernel<<<dim3(NBB * 25, 16), 256, 0, stream>>>(
                C, conv_w, (pass == 0) ? buffer : (const float*)out, out, bb0);
        }
    }
}

// Round 3
// 2731.475 us; speedup vs baseline: 1.5781x; 1.5781x over previous
//
#include <hip/hip_runtime.h>
#include <math.h>
#include <stdint.h>

typedef __attribute__((ext_vector_type(8))) short bf16x8;
typedef __attribute__((ext_vector_type(4))) float f32x4;

static __device__ __forceinline__ unsigned short f2bf(float f) {
    unsigned u = __builtin_bit_cast(unsigned, f);
    unsigned r = u + 0x7fffu + ((u >> 16) & 1u);   // RNE
    return (unsigned short)(r >> 16);
}

// ---------------------------------------------------------------------------
// gather pass1: x0[t'][cc] = src[bb][cc][u*5+v][y][x], l=u*32+y, col=lb*160+v*32+x
__global__ __launch_bounds__(256) void gather1(const float* __restrict__ src, float* __restrict__ x0,
                                               int W, int bb0) {
    int cct = blockIdx.x & 3, y = blockIdx.x >> 2;
    int n = blockIdx.y; int u = n / 5, v = n % 5;
    int lb = blockIdx.z, bb = bb0 + lb;
    __shared__ float tile[32][33];
    int tx = threadIdx.x & 31, tg = threadIdx.x >> 5;
    const float* s = src + (((size_t)(bb * 128 + cct * 32) * 25 + n) * 32 + y) * 32;
    #pragma unroll
    for (int i = 0; i < 4; i++) {
        int cl = tg + 8 * i;
        tile[cl][tx] = s[(size_t)cl * 25600 + tx];      // [cc_local][x]
    }
    __syncthreads();
    float* d = x0 + ((size_t)(u * 32 + y) * W + lb * 160 + v * 32) * 128 + cct * 32;
    #pragma unroll
    for (int i = 0; i < 4; i++) {
        int xx = tg + 8 * i;
        d[(size_t)xx * 128 + tx] = tile[tx][xx];
    }
}

// gather pass2: x0[t'][cc] = src[bb][cc][u*5+v][y][x], l=v*32+x, col=lb*160+u*32+y
__global__ __launch_bounds__(256) void gather2(const float* __restrict__ src, float* __restrict__ x0,
                                               int W, int bb0) {
    int cct = blockIdx.x & 3, x = blockIdx.x >> 2;
    int n = blockIdx.y; int u = n / 5, v = n % 5;
    int lb = blockIdx.z, bb = bb0 + lb;
    __shared__ float tile[32][33];
    int tx = threadIdx.x & 31, tg = threadIdx.x >> 5;
    const float* s = src + (((size_t)(bb * 128 + cct * 32) * 25 + n) * 32) * 32 + x;
    #pragma unroll
    for (int i = 0; i < 4; i++) {
        int cl = tg + 8 * i;
        tile[cl][tx] = s[(size_t)cl * 25600 + tx * 32];  // [cc_local][y]
    }
    __syncthreads();
    float* d = x0 + ((size_t)(v * 32 + x) * W + lb * 160 + u * 32) * 128 + cct * 32;
    #pragma unroll
    for (int i = 0; i < 4; i++) {
        int yy = tg + 8 * i;
        d[(size_t)yy * 128 + tx] = tile[tx][yy];
    }
}

// scatter pass1: xs[lb][cc][u*5+v][y][x] = ot[(u*32+y)*W + lb*160 + v*32+x][cc]
__global__ __launch_bounds__(256) void scatter1(const float* __restrict__ ot, float* __restrict__ xs,
                                                int W) {
    int cct = blockIdx.x & 3, y = blockIdx.x >> 2;
    int n = blockIdx.y; int u = n / 5, v = n % 5;
    int lb = blockIdx.z;
    __shared__ float tile[32][33];
    int tx = threadIdx.x & 31, tg = threadIdx.x >> 5;
    const float* s = ot + ((size_t)(u * 32 + y) * W + lb * 160 + v * 32) * 128 + cct * 32;
    #pragma unroll
    for (int i = 0; i < 4; i++) {
        int xx = tg + 8 * i;
        tile[xx][tx] = s[(size_t)xx * 128 + tx];         // [x][cc_local]
    }
    __syncthreads();
    float* d = xs + (((size_t)(lb * 128 + cct * 32) * 25 + n) * 32 + y) * 32;
    #pragma unroll
    for (int i = 0; i < 4; i++) {
        int cl = tg + 8 * i;
        d[(size_t)cl * 25600 + tx] = tile[tx][cl];
    }
}

// scatter pass2: xs[lb][cc][u*5+v][y][x] = ot[(v*32+x)*W + lb*160 + u*32+y][cc]
__global__ __launch_bounds__(256) void scatter2(const float* __restrict__ ot, float* __restrict__ xs,
                                                int W) {
    int cct = blockIdx.x & 3, y = blockIdx.x >> 2;
    int n = blockIdx.y; int u = n / 5, v = n % 5;
    int lb = blockIdx.z;
    __shared__ float tile[32][33];
    int tx = threadIdx.x & 31, tg = threadIdx.x >> 5;
    const float* s = ot + ((size_t)(lb * 160 + u * 32 + y)) * 128 + cct * 32;
    #pragma unroll
    for (int i = 0; i < 4; i++) {
        int xx = tg + 8 * i;
        tile[xx][tx] = s[(size_t)(v * 32 + xx) * W * 128 + tx];
    }
    __syncthreads();
    float* d = xs + (((size_t)(lb * 128 + cct * 32) * 25 + n) * 32 + y) * 32;
    #pragma unroll
    for (int i = 0; i < 4; i++) {
        int cl = tg + 8 * i;
        d[(size_t)cl * 25600 + tx] = tile[tx][cl];
    }
}

// ---------------------------------------------------------------------------
// LayerNorm over E=256, one wave per token, 4 tokens per block
__global__ __launch_bounds__(256) void ln_kernel(const float* __restrict__ in, float* __restrict__ out,
                                                 const float* __restrict__ w, const float* __restrict__ b) {
    int tok = blockIdx.x * 4 + (threadIdx.x >> 6);
    int lane = threadIdx.x & 63;
    const float4 v4 = ((const float4*)(in + (size_t)tok * 256))[lane];
    float s = v4.x + v4.y + v4.z + v4.w;
    #pragma unroll
    for (int off = 32; off > 0; off >>= 1) s += __shfl_xor(s, off);
    float mu = s * (1.0f / 256.0f);
    float dx = v4.x - mu, dy = v4.y - mu, dz = v4.z - mu, dw = v4.w - mu;
    float vs = dx * dx + dy * dy + dz * dz + dw * dw;
    #pragma unroll
    for (int off = 32; off > 0; off >>= 1) vs += __shfl_xor(vs, off);
    float inv = rsqrtf(vs * (1.0f / 256.0f) + 1e-5f);
    float4 wv = ((const float4*)w)[lane];
    float4 bv = ((const float4*)b)[lane];
    float4 o4;
    o4.x = dx * inv * wv.x + bv.x;
    o4.y = dy * inv * wv.y + bv.y;
    o4.z = dz * inv * wv.z + bv.z;
    o4.w = dw * inv * wv.w + bv.w;
    ((float4*)(out + (size_t)tok * 256))[lane] = o4;
}

// ---------------------------------------------------------------------------
// bf16-MFMA GEMM: Y[M,N] = X[M,K] @ Wt[N,K]^T (+R) (relu?)
// Tiles 128x128, BK=64. fp32 inputs converted RNE->bf16 during LDS staging.
// LDS tiles [128][64] bf16 with byte ^= ((row&7)<<4) swizzle (conflict-free
// ds_read_b128: 8 consecutive rows -> 8 distinct 16B slots).
__global__ __launch_bounds__(256) void gemm_mfma(const float* __restrict__ X,
                                                 const float* __restrict__ Wt,
                                                 float* __restrict__ Y, const float* __restrict__ R,
                                                 int N, int K, int relu) {
    __shared__ short As[128 * 64];
    __shared__ short Bs[128 * 64];
    const int bm = blockIdx.x * 128, bn = blockIdx.y * 128;
    const int tid = threadIdx.x;
    const int lane = tid & 63, w = tid >> 6;
    const int wm = (w >> 1) * 64, wn = (w & 1) * 64;
    const int lr = lane & 15, lq = lane >> 4;
    f32x4 acc[4][4];
    #pragma unroll
    for (int m = 0; m < 4; m++)
        #pragma unroll
        for (int n = 0; n < 4; n++)
            acc[m][n] = (f32x4){0.f, 0.f, 0.f, 0.f};

    for (int k0 = 0; k0 < K; k0 += 64) {
        #pragma unroll
        for (int i = 0; i < 8; i++) {
            int id = tid + 256 * i;              // 0..2047
            int row = id >> 4, cg = id & 15;     // row 0..127, col-group of 4
            float4 va = *(const float4*)(X  + (size_t)(bm + row) * K + k0 + cg * 4);
            float4 vb = *(const float4*)(Wt + (size_t)(bn + row) * K + k0 + cg * 4);
            ushort4 ba, bb;
            ba.x = f2bf(va.x); ba.y = f2bf(va.y); ba.z = f2bf(va.z); ba.w = f2bf(va.w);
            bb.x = f2bf(vb.x); bb.y = f2bf(vb.y); bb.z = f2bf(vb.z); bb.w = f2bf(vb.w);
            int boff = row * 128 + ((cg * 8) ^ ((row & 7) << 4));
            *(ushort4*)((char*)As + boff) = ba;
            *(ushort4*)((char*)Bs + boff) = bb;
        }
        __syncthreads();
        #pragma unroll
        for (int ks = 0; ks < 2; ks++) {
            bf16x8 af[4], bf[4];
            #pragma unroll
            for (int m = 0; m < 4; m++) {
                int row = wm + m * 16 + lr;
                int boff = row * 128 + ((ks * 64 + lq * 16) ^ ((row & 7) << 4));
                af[m] = *(const bf16x8*)((const char*)As + boff);
            }
            #pragma unroll
            for (int n = 0; n < 4; n++) {
                int row = wn + n * 16 + lr;
                int boff = row * 128 + ((ks * 64 + lq * 16) ^ ((row & 7) << 4));
                bf[n] = *(const bf16x8*)((const char*)Bs + boff);
            }
            #pragma unroll
            for (int m = 0; m < 4; m++)
                #pragma unroll
                for (int n = 0; n < 4; n++)
                    acc[m][n] = __builtin_amdgcn_mfma_f32_16x16x32_bf16(af[m], bf[n], acc[m][n], 0, 0, 0);
        }
        __syncthreads();
    }
    // epilogue: C/D map col=lane&15, row=(lane>>4)*4+reg
    #pragma unroll
    for (int m = 0; m < 4; m++) {
        int row0 = bm + wm + m * 16 + lq * 4;
        #pragma unroll
        for (int r = 0; r < 4; r++) {
            size_t rowoff = (size_t)(row0 + r) * N;
            #pragma unroll
            for (int n = 0; n < 4; n++) {
                int col = bn + wn + n * 16 + lr;
                float val = acc[m][n][r];
                if (R) val += R[rowoff + col];
                if (relu) val = fmaxf(val, 0.0f);
                Y[rowoff + col] = val;
            }
        }
    }
}

// ---------------------------------------------------------------------------
// Attention: one block per (col, head). L=160, hd=32. Banded mask:
// query (uq,yq) attends keys (uk, yk) for all uk, yk in [yq-5, yq+5].
__global__ __launch_bounds__(256) void attn_kernel(const float* __restrict__ qk,
                                                   const float* __restrict__ v,
                                                   float* __restrict__ o, int W) {
    const int bidx = blockIdx.x >> 3;
    const int h = blockIdx.x & 7;
    __shared__ float ks[160][36], vs[160][36];
    const int tid = threadIdx.x;
    for (int idx = tid; idx < 160 * 32; idx += 256) {
        int l = idx >> 5, d = idx & 31;
        size_t base = (size_t)l * W + bidx;
        ks[l][d] = qk[base * 512 + 256 + h * 32 + d];
        vs[l][d] = v[base * 256 + h * 32 + d];
    }
    __syncthreads();
    if (tid >= 160) return;
    const int yq = tid & 31;
    float4 qr[8];
    {
        const float4* qp = (const float4*)(qk + ((size_t)tid * W + bidx) * 512 + h * 32);
        #pragma unroll
        for (int i = 0; i < 8; i++) qr[i] = qp[i];
    }
    float s[5][11];
    float mx = -1e30f;
    #pragma unroll
    for (int uk = 0; uk < 5; uk++) {
        #pragma unroll
        for (int t = 0; t < 11; t++) {
            int yk = yq - 5 + t;
            float sc = -1e30f;
            if ((unsigned)yk < 32u) {
                const float4* kp = (const float4*)(&ks[uk * 32 + yk][0]);
                float d0 = 0.0f;
                #pragma unroll
                for (int i = 0; i < 8; i++) {
                    float4 kv = kp[i];
                    d0 = fmaf(qr[i].x, kv.x, d0);
                    d0 = fmaf(qr[i].y, kv.y, d0);
                    d0 = fmaf(qr[i].z, kv.z, d0);
                    d0 = fmaf(qr[i].w, kv.w, d0);
                }
                sc = d0 * 0.17677669529663687f;  // 1/sqrt(32)
            }
            s[uk][t] = sc;
            mx = fmaxf(mx, sc);
        }
    }
    float sum = 0.0f;
    float4 oa[8] = {};
    #pragma unroll
    for (int uk = 0; uk < 5; uk++) {
        #pragma unroll
        for (int t = 0; t < 11; t++) {
            int yk = yq - 5 + t;
            if ((unsigned)yk < 32u) {
                float p = __expf(s[uk][t] - mx);
                sum += p;
                const float4* vp = (const float4*)(&vs[uk * 32 + yk][0]);
                #pragma unroll
                for (int i = 0; i < 8; i++) {
                    float4 vv4 = vp[i];
                    oa[i].x = fmaf(p, vv4.x, oa[i].x);
                    oa[i].y = fmaf(p, vv4.y, oa[i].y);
                    oa[i].z = fmaf(p, vv4.z, oa[i].z);
                    oa[i].w = fmaf(p, vv4.w, oa[i].w);
                }
            }
        }
    }
    float inv = 1.0f / sum;
    float* op = o + ((size_t)tid * W + bidx) * 256 + h * 32;
    #pragma unroll
    for (int i = 0; i < 8; i++) {
        op[i * 4 + 0] = oa[i].x * inv;
        op[i * 4 + 1] = oa[i].y * inv;
        op[i * 4 + 2] = oa[i].z * inv;
        op[i * 4 + 3] = oa[i].w * inv;
    }
}

// ---------------------------------------------------------------------------
// 3x3 conv (per depth slice), 128->128 ch, pad 1, + residual.
// grid (NBB*25, 32): 4 co per block for occupancy. In-place res==out safe.
__global__ __launch_bounds__(256) void conv_kernel(const float* __restrict__ in,
                                                   const float* __restrict__ wgt,
                                                   const float* __restrict__ res,
                                                   float* __restrict__ out, int bb0) {
    const int slice = blockIdx.x;
    const int lb = slice / 25, n = slice % 25;
    const int bb = bb0 + lb;
    const int cot = blockIdx.y;               // 0..31, 4 co each
    __shared__ float ins[8][34][34];
    const int tid = threadIdx.x;
    const int tx = tid & 31, yg = tid >> 5;
    float acc[4][4] = {};
    const float* inbase = in + ((size_t)lb * 128 * 25 + n) * 1024;
    for (int ci0 = 0; ci0 < 128; ci0 += 8) {
        for (int idx = tid; idx < 8 * 34 * 34; idx += 256) {
            int ci = idx / 1156, rem = idx % 1156;
            int yy = rem / 34, xx = rem % 34;
            int gy = yy - 1, gx = xx - 1;
            float val = 0.0f;
            if (gy >= 0 && gy < 32 && gx >= 0 && gx < 32)
                val = inbase[(size_t)(ci0 + ci) * 25600 + gy * 32 + gx];
            ins[ci][yy][xx] = val;
        }
        __syncthreads();
        #pragma unroll
        for (int ci = 0; ci < 8; ci++) {
            float pix[6][3];
            #pragma unroll
            for (int r = 0; r < 6; r++)
                #pragma unroll
                for (int c = 0; c < 3; c++)
                    pix[r][c] = ins[ci][yg * 4 + r][tx + c];
            #pragma unroll
            for (int co = 0; co < 4; co++) {
                const float* wp = wgt + ((size_t)(cot * 4 + co) * 128 + ci0 + ci) * 9;
                float w0 = wp[0], w1 = wp[1], w2 = wp[2];
                float w3 = wp[3], w4 = wp[4], w5 = wp[5];
                float w6 = wp[6], w7 = wp[7], w8 = wp[8];
                #pragma unroll
                for (int yy = 0; yy < 4; yy++) {
                    float a = acc[co][yy];
                    a = fmaf(pix[yy + 0][0], w0, a);
                    a = fmaf(pix[yy + 0][1], w1, a);
                    a = fmaf(pix[yy + 0][2], w2, a);
                    a = fmaf(pix[yy + 1][0], w3, a);
                    a = fmaf(pix[yy + 1][1], w4, a);
                    a = fmaf(pix[yy + 1][2], w5, a);
                    a = fmaf(pix[yy + 2][0], w6, a);
                    a = fmaf(pix[yy + 2][1], w7, a);
                    a = fmaf(pix[yy + 2][2], w8, a);
                    acc[co][yy] = a;
                }
            }
        }
        __syncthreads();
    }
    #pragma unroll
    for (int co = 0; co < 4; co++) {
        #pragma unroll
        for (int yy = 0; yy < 4; yy++) {
            size_t off = (((size_t)(bb * 128 + cot * 4 + co) * 25 + n) * 32 + (yg * 4 + yy)) * 32 + tx;
            out[off] = acc[co][yy] + res[off];
        }
    }
}

// ---------------------------------------------------------------------------
extern "C" void kernel_launch(void* const* d_in, const int* in_sizes, int n_in,
                              void* d_out, int out_size, void* d_ws, size_t ws_size,
                              hipStream_t stream) {
    (void)in_sizes; (void)n_in; (void)out_size;
    const float* buffer     = (const float*)d_in[0];
    const float* Win        = (const float*)d_in[1];
    const float* ln_w       = (const float*)d_in[2];
    const float* ln_b       = (const float*)d_in[3];
    const float* in_proj    = (const float*)d_in[4];
    const float* attn_out_w = (const float*)d_in[5];
    const float* ffn_ln_w   = (const float*)d_in[6];
    const float* ffn_ln_b   = (const float*)d_in[7];
    const float* ff1        = (const float*)d_in[8];
    const float* ff2        = (const float*)d_in[9];
    const float* Wout       = (const float*)d_in[10];
    const float* conv_w     = (const float*)d_in[11];
    float* out = (float*)d_out;
    float* ws  = (float*)d_ws;

    // Chunking over bb: scratch = T*1408 floats, T = NBB*25600.
    int NBB = (ws_size >= (size_t)2 * 25600 * 1408 * 4) ? 2 : 1;
    const int W = NBB * 160;
    const size_t T = (size_t)NBB * 25600;

    float* x0  = ws;                  // T*128
    float* A   = ws + T * 128;        // T*256  tok (residual stream)
    float* B   = ws + T * 384;        // T*256  tn / vv / tn2
    float* C   = ws + T * 640;        // T*512  qk / ffn hidden / scatter buf
    float* D   = ws + T * 1152;       // T*256  attn out

    const int GM = (int)(T / 128);

    for (int pass = 0; pass < 2; pass++) {
        const float* src = (pass == 0) ? buffer : out;
        for (int bb0 = 0; bb0 < 2; bb0 += NBB) {
            if (pass == 0) gather1<<<dim3(128, 25, NBB), 256, 0, stream>>>(src, x0, W, bb0);
            else           gather2<<<dim3(128, 25, NBB), 256, 0, stream>>>(src, x0, W, bb0);

            // tok = x0 @ Win^T                  (K=128 -> N=256)
            gemm_mfma<<<dim3(GM, 2), 256, 0, stream>>>(x0, Win, A, nullptr, 256, 128, 0);
            // tn = LN(tok)
            ln_kernel<<<(int)(T / 4), 256, 0, stream>>>(A, B, ln_w, ln_b);
            // qk = tn @ [Wq;Wk]^T               (N=512)
            gemm_mfma<<<dim3(GM, 4), 256, 0, stream>>>(B, in_proj, C, nullptr, 512, 256, 0);
            // vv = tok @ Wv^T (un-normed tok) -> overwrite B
            gemm_mfma<<<dim3(GM, 2), 256, 0, stream>>>(A, in_proj + (size_t)512 * 256, B, nullptr, 256, 256, 0);
            // attention
            attn_kernel<<<W * 8, 256, 0, stream>>>(C, B, D, W);
            // tok = ob @ attn_out_w^T + tok  (in-place residual on A)
            gemm_mfma<<<dim3(GM, 2), 256, 0, stream>>>(D, attn_out_w, A, A, 256, 256, 0);
            // tn2 = LN_ffn(tok)
            ln_kernel<<<(int)(T / 4), 256, 0, stream>>>(A, B, ffn_ln_w, ffn_ln_b);
            // hidden = relu(tn2 @ ff1^T)        (N=512)
            gemm_mfma<<<dim3(GM, 4), 256, 0, stream>>>(B, ff1, C, nullptr, 512, 256, 1);
            // tok = hidden @ ff2^T + tok        (K=512)
            gemm_mfma<<<dim3(GM, 2), 256, 0, stream>>>(C, ff2, A, A, 256, 512, 0);
            // ot = tok @ Wout^T                 (N=128) -> x0 region
            gemm_mfma<<<dim3(GM, 1), 256, 0, stream>>>(A, Wout, x0, nullptr, 128, 256, 0);

            if (pass == 0) scatter1<<<dim3(128, 25, NBB), 256, 0, stream>>>(x0, C, W);
            else           scatter2<<<dim3(128, 25, NBB), 256, 0, stream>>>(x0, C, W);

            conv_kernel<<<dim3(NBB * 25, 32), 256, 0, stream>>>(
                C, conv_w, (pass == 0) ? buffer : (const float*)out, out, bb0);
        }
    }
}

// Round 4
// 1668.175 us; speedup vs baseline: 2.5839x; 1.6374x over previous
//
#include <hip/hip_runtime.h>
#include <math.h>
#include <stdint.h>

typedef __attribute__((ext_vector_type(8))) short bf16x8;
typedef __attribute__((ext_vector_type(4))) float f32x4;

static __device__ __forceinline__ unsigned short f2bf(float f) {
    unsigned u = __builtin_bit_cast(unsigned, f);
    unsigned r = u + 0x7fffu + ((u >> 16) & 1u);   // RNE
    return (unsigned short)(r >> 16);
}

// ---------------------------------------------------------------------------
// gather pass1: x0[t'][cc] = src[bb][cc][u*5+v][y][x], l=u*32+y, col=lb*160+v*32+x
__global__ __launch_bounds__(256) void gather1(const float* __restrict__ src, float* __restrict__ x0,
                                               int W, int bb0) {
    int cct = blockIdx.x & 3, y = blockIdx.x >> 2;
    int n = blockIdx.y; int u = n / 5, v = n % 5;
    int lb = blockIdx.z, bb = bb0 + lb;
    __shared__ float tile[32][33];
    int tx = threadIdx.x & 31, tg = threadIdx.x >> 5;
    const float* s = src + (((size_t)(bb * 128 + cct * 32) * 25 + n) * 32 + y) * 32;
    #pragma unroll
    for (int i = 0; i < 4; i++) {
        int cl = tg + 8 * i;
        tile[cl][tx] = s[(size_t)cl * 25600 + tx];      // [cc_local][x]
    }
    __syncthreads();
    float* d = x0 + ((size_t)(u * 32 + y) * W + lb * 160 + v * 32) * 128 + cct * 32;
    #pragma unroll
    for (int i = 0; i < 4; i++) {
        int xx = tg + 8 * i;
        d[(size_t)xx * 128 + tx] = tile[tx][xx];
    }
}

// gather pass2: x0[t'][cc] = src[bb][cc][u*5+v][y][x], l=v*32+x, col=lb*160+u*32+y
__global__ __launch_bounds__(256) void gather2(const float* __restrict__ src, float* __restrict__ x0,
                                               int W, int bb0) {
    int cct = blockIdx.x & 3, x = blockIdx.x >> 2;
    int n = blockIdx.y; int u = n / 5, v = n % 5;
    int lb = blockIdx.z, bb = bb0 + lb;
    __shared__ float tile[32][33];
    int tx = threadIdx.x & 31, tg = threadIdx.x >> 5;
    const float* s = src + (((size_t)(bb * 128 + cct * 32) * 25 + n) * 32) * 32 + x;
    #pragma unroll
    for (int i = 0; i < 4; i++) {
        int cl = tg + 8 * i;
        tile[cl][tx] = s[(size_t)cl * 25600 + tx * 32];  // [cc_local][y]
    }
    __syncthreads();
    float* d = x0 + ((size_t)(v * 32 + x) * W + lb * 160 + u * 32) * 128 + cct * 32;
    #pragma unroll
    for (int i = 0; i < 4; i++) {
        int yy = tg + 8 * i;
        d[(size_t)yy * 128 + tx] = tile[tx][yy];
    }
}

// ---------------------------------------------------------------------------
// scatterP pass1: xp[(lb*25 + u*5+v)][y*32+x][cc] (bf16) = ot[t][cc],
//   t = (u*32+y)*W + lb*160 + v*32+x.  grid (32=y, 25=n, NBB)
__global__ __launch_bounds__(256) void scatterP1(const float* __restrict__ ot,
                                                 unsigned short* __restrict__ xp, int W) {
    int y = blockIdx.x, n = blockIdx.y, lb = blockIdx.z;
    int u = n / 5, v = n % 5;
    int x = threadIdx.x >> 3, cg = threadIdx.x & 7;
    size_t t = (size_t)(u * 32 + y) * W + lb * 160 + v * 32 + x;
    const float4* s = (const float4*)(ot + t * 128 + cg * 16);
    float4 a = s[0], b = s[1], c = s[2], d = s[3];
    ushort4 o0, o1, o2, o3;
    o0.x = f2bf(a.x); o0.y = f2bf(a.y); o0.z = f2bf(a.z); o0.w = f2bf(a.w);
    o1.x = f2bf(b.x); o1.y = f2bf(b.y); o1.z = f2bf(b.z); o1.w = f2bf(b.w);
    o2.x = f2bf(c.x); o2.y = f2bf(c.y); o2.z = f2bf(c.z); o2.w = f2bf(c.w);
    o3.x = f2bf(d.x); o3.y = f2bf(d.y); o3.z = f2bf(d.z); o3.w = f2bf(d.w);
    ushort4* dp = (ushort4*)(xp + (((size_t)(lb * 25 + n) * 1024 + y * 32 + x) * 128 + cg * 16));
    dp[0] = o0; dp[1] = o1; dp[2] = o2; dp[3] = o3;
}

// scatterP pass2: xp[(lb*25 + u*5+v)][y*32+x][cc] = ot[t][cc],
//   t = (v*32+x)*W + lb*160 + u*32+y
__global__ __launch_bounds__(256) void scatterP2(const float* __restrict__ ot,
                                                 unsigned short* __restrict__ xp, int W) {
    int y = blockIdx.x, n = blockIdx.y, lb = blockIdx.z;
    int u = n / 5, v = n % 5;
    int x = threadIdx.x >> 3, cg = threadIdx.x & 7;
    size_t t = (size_t)(v * 32 + x) * W + lb * 160 + u * 32 + y;
    const float4* s = (const float4*)(ot + t * 128 + cg * 16);
    float4 a = s[0], b = s[1], c = s[2], d = s[3];
    ushort4 o0, o1, o2, o3;
    o0.x = f2bf(a.x); o0.y = f2bf(a.y); o0.z = f2bf(a.z); o0.w = f2bf(a.w);
    o1.x = f2bf(b.x); o1.y = f2bf(b.y); o1.z = f2bf(b.z); o1.w = f2bf(b.w);
    o2.x = f2bf(c.x); o2.y = f2bf(c.y); o2.z = f2bf(c.z); o2.w = f2bf(c.w);
    o3.x = f2bf(d.x); o3.y = f2bf(d.y); o3.z = f2bf(d.z); o3.w = f2bf(d.w);
    ushort4* dp = (ushort4*)(xp + (((size_t)(lb * 25 + n) * 1024 + y * 32 + x) * 128 + cg * 16));
    dp[0] = o0; dp[1] = o1; dp[2] = o2; dp[3] = o3;
}

// ---------------------------------------------------------------------------
// conv weight repack: conv_w[co][ci][tap(9)] f32 -> wb[tap][co][ci] bf16
__global__ __launch_bounds__(256) void repack_w(const float* __restrict__ cw,
                                                unsigned short* __restrict__ wb) {
    int g = blockIdx.x * 256 + threadIdx.x;     // 147456 total
    int co = g / 1152;
    int rem = g - co * 1152;
    int ci = rem / 9, tap = rem - ci * 9;
    wb[((size_t)tap * 128 + co) * 128 + ci] = f2bf(cw[g]);
}

// ---------------------------------------------------------------------------
// LayerNorm over E=256, one wave per token, 4 tokens per block
__global__ __launch_bounds__(256) void ln_kernel(const float* __restrict__ in, float* __restrict__ out,
                                                 const float* __restrict__ w, const float* __restrict__ b) {
    int tok = blockIdx.x * 4 + (threadIdx.x >> 6);
    int lane = threadIdx.x & 63;
    const float4 v4 = ((const float4*)(in + (size_t)tok * 256))[lane];
    float s = v4.x + v4.y + v4.z + v4.w;
    #pragma unroll
    for (int off = 32; off > 0; off >>= 1) s += __shfl_xor(s, off);
    float mu = s * (1.0f / 256.0f);
    float dx = v4.x - mu, dy = v4.y - mu, dz = v4.z - mu, dw = v4.w - mu;
    float vs = dx * dx + dy * dy + dz * dz + dw * dw;
    #pragma unroll
    for (int off = 32; off > 0; off >>= 1) vs += __shfl_xor(vs, off);
    float inv = rsqrtf(vs * (1.0f / 256.0f) + 1e-5f);
    float4 wv = ((const float4*)w)[lane];
    float4 bv = ((const float4*)b)[lane];
    float4 o4;
    o4.x = dx * inv * wv.x + bv.x;
    o4.y = dy * inv * wv.y + bv.y;
    o4.z = dz * inv * wv.z + bv.z;
    o4.w = dw * inv * wv.w + bv.w;
    ((float4*)(out + (size_t)tok * 256))[lane] = o4;
}

// ---------------------------------------------------------------------------
// bf16-MFMA GEMM: Y[M,N] = X[M,K] @ Wt[N,K]^T (+R) (relu?)  128x128, BK=64
__global__ __launch_bounds__(256) void gemm_mfma(const float* __restrict__ X,
                                                 const float* __restrict__ Wt,
                                                 float* __restrict__ Y, const float* __restrict__ R,
                                                 int N, int K, int relu) {
    __shared__ short As[128 * 64];
    __shared__ short Bs[128 * 64];
    const int bm = blockIdx.x * 128, bn = blockIdx.y * 128;
    const int tid = threadIdx.x;
    const int lane = tid & 63, w = tid >> 6;
    const int wm = (w >> 1) * 64, wn = (w & 1) * 64;
    const int lr = lane & 15, lq = lane >> 4;
    f32x4 acc[4][4];
    #pragma unroll
    for (int m = 0; m < 4; m++)
        #pragma unroll
        for (int n = 0; n < 4; n++)
            acc[m][n] = (f32x4){0.f, 0.f, 0.f, 0.f};

    for (int k0 = 0; k0 < K; k0 += 64) {
        #pragma unroll
        for (int i = 0; i < 8; i++) {
            int id = tid + 256 * i;              // 0..2047
            int row = id >> 4, cg = id & 15;     // row 0..127, col-group of 4
            float4 va = *(const float4*)(X  + (size_t)(bm + row) * K + k0 + cg * 4);
            float4 vb = *(const float4*)(Wt + (size_t)(bn + row) * K + k0 + cg * 4);
            ushort4 ba, bb;
            ba.x = f2bf(va.x); ba.y = f2bf(va.y); ba.z = f2bf(va.z); ba.w = f2bf(va.w);
            bb.x = f2bf(vb.x); bb.y = f2bf(vb.y); bb.z = f2bf(vb.z); bb.w = f2bf(vb.w);
            int boff = row * 128 + ((cg * 8) ^ ((row & 7) << 4));
            *(ushort4*)((char*)As + boff) = ba;
            *(ushort4*)((char*)Bs + boff) = bb;
        }
        __syncthreads();
        #pragma unroll
        for (int ks = 0; ks < 2; ks++) {
            bf16x8 af[4], bf[4];
            #pragma unroll
            for (int m = 0; m < 4; m++) {
                int row = wm + m * 16 + lr;
                int boff = row * 128 + ((ks * 64 + lq * 16) ^ ((row & 7) << 4));
                af[m] = *(const bf16x8*)((const char*)As + boff);
            }
            #pragma unroll
            for (int n = 0; n < 4; n++) {
                int row = wn + n * 16 + lr;
                int boff = row * 128 + ((ks * 64 + lq * 16) ^ ((row & 7) << 4));
                bf[n] = *(const bf16x8*)((const char*)Bs + boff);
            }
            #pragma unroll
            for (int m = 0; m < 4; m++)
                #pragma unroll
                for (int n = 0; n < 4; n++)
                    acc[m][n] = __builtin_amdgcn_mfma_f32_16x16x32_bf16(af[m], bf[n], acc[m][n], 0, 0, 0);
        }
        __syncthreads();
    }
    #pragma unroll
    for (int m = 0; m < 4; m++) {
        int row0 = bm + wm + m * 16 + lq * 4;
        #pragma unroll
        for (int r = 0; r < 4; r++) {
            size_t rowoff = (size_t)(row0 + r) * N;
            #pragma unroll
            for (int n = 0; n < 4; n++) {
                int col = bn + wn + n * 16 + lr;
                float val = acc[m][n][r];
                if (R) val += R[rowoff + col];
                if (relu) val = fmaxf(val, 0.0f);
                Y[rowoff + col] = val;
            }
        }
    }
}

// ---------------------------------------------------------------------------
// conv as implicit MFMA GEMM. xp: [slice][1024 pix][128 ci] bf16 (chunk-local),
// wb: [9 tap][128 co][128 ci] bf16. K = 9*128, BK=64 (18 steps).
// Block: 128 co x 128 pix (ptile = 4 image rows). mfma(w_frag, x_frag) puts
// pixels in the C/D lane (col) dim -> channel-major epilogue stores are
// 4x64B contiguous segments per wave.
__global__ __launch_bounds__(256) void conv_mfma(const unsigned short* __restrict__ xp,
                                                 const unsigned short* __restrict__ wb,
                                                 const float* __restrict__ res,
                                                 float* __restrict__ out, int bb0) {
    const int ptile = blockIdx.x;               // 0..7
    const int slice = blockIdx.y;               // lb*25 + n
    const int lb = slice / 25, n = slice % 25;
    const int bb = bb0 + lb;
    const int y0 = ptile * 4;
    __shared__ unsigned short As[128 * 64];     // pixels x ci
    __shared__ unsigned short Bs[128 * 64];     // co x ci
    const int tid = threadIdx.x;
    const int lane = tid & 63, w = tid >> 6;
    const int wm = (w >> 1) * 64;               // co half
    const int wn = (w & 1) * 64;                // pixel half
    const int lr = lane & 15, lq = lane >> 4;
    const unsigned short* xs = xp + (size_t)slice * 1024 * 128;
    f32x4 acc[4][4];
    #pragma unroll
    for (int m = 0; m < 4; m++)
        #pragma unroll
        for (int nn = 0; nn < 4; nn++)
            acc[m][nn] = (f32x4){0.f, 0.f, 0.f, 0.f};

    for (int tap = 0; tap < 9; tap++) {
        const int dy = tap / 3 - 1, dx = tap % 3 - 1;
        for (int c0 = 0; c0 < 128; c0 += 64) {
            #pragma unroll
            for (int i = 0; i < 4; i++) {
                int id = tid + 256 * i;          // 0..1023
                int row = id >> 3, cg = id & 7;  // pixel row, 16B col-group
                int py = y0 + (row >> 5) + dy;
                int px = (row & 31) + dx;
                uint4 v = {0u, 0u, 0u, 0u};
                if ((unsigned)py < 32u && (unsigned)px < 32u)
                    v = *(const uint4*)(xs + ((size_t)(py * 32 + px) * 128 + c0 + cg * 8));
                int boff = row * 128 + ((cg * 16) ^ ((row & 7) << 4));
                *(uint4*)((char*)As + boff) = v;
            }
            #pragma unroll
            for (int i = 0; i < 4; i++) {
                int id = tid + 256 * i;
                int row = id >> 3, cg = id & 7;  // co row
                uint4 v = *(const uint4*)(wb + (((size_t)tap * 128 + row) * 128 + c0 + cg * 8));
                int boff = row * 128 + ((cg * 16) ^ ((row & 7) << 4));
                *(uint4*)((char*)Bs + boff) = v;
            }
            __syncthreads();
            #pragma unroll
            for (int ks = 0; ks < 2; ks++) {
                bf16x8 wf[4], xf[4];
                #pragma unroll
                for (int m = 0; m < 4; m++) {
                    int row = wm + m * 16 + lr;
                    int boff = row * 128 + ((ks * 64 + lq * 16) ^ ((row & 7) << 4));
                    wf[m] = *(const bf16x8*)((const char*)Bs + boff);
                }
                #pragma unroll
                for (int nn = 0; nn < 4; nn++) {
                    int row = wn + nn * 16 + lr;
                    int boff = row * 128 + ((ks * 64 + lq * 16) ^ ((row & 7) << 4));
                    xf[nn] = *(const bf16x8*)((const char*)As + boff);
                }
                #pragma unroll
                for (int m = 0; m < 4; m++)
                    #pragma unroll
                    for (int nn = 0; nn < 4; nn++)
                        acc[m][nn] = __builtin_amdgcn_mfma_f32_16x16x32_bf16(wf[m], xf[nn], acc[m][nn], 0, 0, 0);
            }
            __syncthreads();
        }
    }
    // epilogue: co = wm + m*16 + lq*4 + r ; pixel = wn + nn*16 + lr
    #pragma unroll
    for (int m = 0; m < 4; m++) {
        int co0 = wm + m * 16 + lq * 4;
        #pragma unroll
        for (int r = 0; r < 4; r++) {
            size_t rowoff = (((size_t)(bb * 128 + co0 + r) * 25 + n) * 1024) + ptile * 128;
            #pragma unroll
            for (int nn = 0; nn < 4; nn++) {
                int pix = wn + nn * 16 + lr;
                out[rowoff + pix] = acc[m][nn][r] + res[rowoff + pix];
            }
        }
    }
}

// ---------------------------------------------------------------------------
// Attention: one block per (col, head). L=160, hd=32. Banded mask.
__global__ __launch_bounds__(256) void attn_kernel(const float* __restrict__ qk,
                                                   const float* __restrict__ v,
                                                   float* __restrict__ o, int W) {
    const int bidx = blockIdx.x >> 3;
    const int h = blockIdx.x & 7;
    __shared__ float ks[160][36], vs[160][36];
    const int tid = threadIdx.x;
    for (int idx = tid; idx < 160 * 32; idx += 256) {
        int l = idx >> 5, d = idx & 31;
        size_t base = (size_t)l * W + bidx;
        ks[l][d] = qk[base * 512 + 256 + h * 32 + d];
        vs[l][d] = v[base * 256 + h * 32 + d];
    }
    __syncthreads();
    if (tid >= 160) return;
    const int yq = tid & 31;
    float4 qr[8];
    {
        const float4* qp = (const float4*)(qk + ((size_t)tid * W + bidx) * 512 + h * 32);
        #pragma unroll
        for (int i = 0; i < 8; i++) qr[i] = qp[i];
    }
    float s[5][11];
    float mx = -1e30f;
    #pragma unroll
    for (int uk = 0; uk < 5; uk++) {
        #pragma unroll
        for (int t = 0; t < 11; t++) {
            int yk = yq - 5 + t;
            float sc = -1e30f;
            if ((unsigned)yk < 32u) {
                const float4* kp = (const float4*)(&ks[uk * 32 + yk][0]);
                float d0 = 0.0f;
                #pragma unroll
                for (int i = 0; i < 8; i++) {
                    float4 kv = kp[i];
                    d0 = fmaf(qr[i].x, kv.x, d0);
                    d0 = fmaf(qr[i].y, kv.y, d0);
                    d0 = fmaf(qr[i].z, kv.z, d0);
                    d0 = fmaf(qr[i].w, kv.w, d0);
                }
                sc = d0 * 0.17677669529663687f;
            }
            s[uk][t] = sc;
            mx = fmaxf(mx, sc);
        }
    }
    float sum = 0.0f;
    float4 oa[8] = {};
    #pragma unroll
    for (int uk = 0; uk < 5; uk++) {
        #pragma unroll
        for (int t = 0; t < 11; t++) {
            int yk = yq - 5 + t;
            if ((unsigned)yk < 32u) {
                float p = __expf(s[uk][t] - mx);
                sum += p;
                const float4* vp = (const float4*)(&vs[uk * 32 + yk][0]);
                #pragma unroll
                for (int i = 0; i < 8; i++) {
                    float4 vv4 = vp[i];
                    oa[i].x = fmaf(p, vv4.x, oa[i].x);
                    oa[i].y = fmaf(p, vv4.y, oa[i].y);
                    oa[i].z = fmaf(p, vv4.z, oa[i].z);
                    oa[i].w = fmaf(p, vv4.w, oa[i].w);
                }
            }
        }
    }
    float inv = 1.0f / sum;
    float* op = o + ((size_t)tid * W + bidx) * 256 + h * 32;
    #pragma unroll
    for (int i = 0; i < 8; i++) {
        op[i * 4 + 0] = oa[i].x * inv;
        op[i * 4 + 1] = oa[i].y * inv;
        op[i * 4 + 2] = oa[i].z * inv;
        op[i * 4 + 3] = oa[i].w * inv;
    }
}

// ---------------------------------------------------------------------------
extern "C" void kernel_launch(void* const* d_in, const int* in_sizes, int n_in,
                              void* d_out, int out_size, void* d_ws, size_t ws_size,
                              hipStream_t stream) {
    (void)in_sizes; (void)n_in; (void)out_size;
    const float* buffer     = (const float*)d_in[0];
    const float* Win        = (const float*)d_in[1];
    const float* ln_w       = (const float*)d_in[2];
    const float* ln_b       = (const float*)d_in[3];
    const float* in_proj    = (const float*)d_in[4];
    const float* attn_out_w = (const float*)d_in[5];
    const float* ffn_ln_w   = (const float*)d_in[6];
    const float* ffn_ln_b   = (const float*)d_in[7];
    const float* ff1        = (const float*)d_in[8];
    const float* ff2        = (const float*)d_in[9];
    const float* Wout       = (const float*)d_in[10];
    const float* conv_w     = (const float*)d_in[11];
    float* out = (float*)d_out;
    float* ws  = (float*)d_ws;

    int NBB = (ws_size >= (size_t)2 * 25600 * 1408 * 4) ? 2 : 1;
    const int W = NBB * 160;
    const size_t T = (size_t)NBB * 25600;

    float* x0  = ws;                  // T*128
    float* A   = ws + T * 128;        // T*256  tok (residual stream)
    float* B   = ws + T * 384;        // T*256  tn / vv / tn2
    float* C   = ws + T * 640;        // T*512  qk / ffn hidden / xp+wb
    float* D   = ws + T * 1152;       // T*256  attn out
    unsigned short* xp = (unsigned short*)C;            // T*128 bf16 (= T*64 floats)
    unsigned short* wb = (unsigned short*)(ws + T * 704); // 147456 bf16

    const int GM = (int)(T / 128);

    for (int pass = 0; pass < 2; pass++) {
        const float* src = (pass == 0) ? buffer : out;
        for (int bb0 = 0; bb0 < 2; bb0 += NBB) {
            if (pass == 0) gather1<<<dim3(128, 25, NBB), 256, 0, stream>>>(src, x0, W, bb0);
            else           gather2<<<dim3(128, 25, NBB), 256, 0, stream>>>(src, x0, W, bb0);

            // tok = x0 @ Win^T                  (K=128 -> N=256)
            gemm_mfma<<<dim3(GM, 2), 256, 0, stream>>>(x0, Win, A, nullptr, 256, 128, 0);
            ln_kernel<<<(int)(T / 4), 256, 0, stream>>>(A, B, ln_w, ln_b);
            // qk = tn @ [Wq;Wk]^T               (N=512)
            gemm_mfma<<<dim3(GM, 4), 256, 0, stream>>>(B, in_proj, C, nullptr, 512, 256, 0);
            // vv = tok @ Wv^T -> overwrite B
            gemm_mfma<<<dim3(GM, 2), 256, 0, stream>>>(A, in_proj + (size_t)512 * 256, B, nullptr, 256, 256, 0);
            attn_kernel<<<W * 8, 256, 0, stream>>>(C, B, D, W);
            // tok += ob @ attn_out_w^T
            gemm_mfma<<<dim3(GM, 2), 256, 0, stream>>>(D, attn_out_w, A, A, 256, 256, 0);
            ln_kernel<<<(int)(T / 4), 256, 0, stream>>>(A, B, ffn_ln_w, ffn_ln_b);
            // hidden = relu(tn2 @ ff1^T)        (N=512)
            gemm_mfma<<<dim3(GM, 4), 256, 0, stream>>>(B, ff1, C, nullptr, 512, 256, 1);
            // tok += hidden @ ff2^T             (K=512)
            gemm_mfma<<<dim3(GM, 2), 256, 0, stream>>>(C, ff2, A, A, 256, 512, 0);
            // ot = tok @ Wout^T                 (N=128) -> x0
            gemm_mfma<<<dim3(GM, 1), 256, 0, stream>>>(A, Wout, x0, nullptr, 128, 256, 0);

            // scatter token-major -> pixel-major bf16 (conv A operand)
            if (pass == 0) scatterP1<<<dim3(32, 25, NBB), 256, 0, stream>>>(x0, xp, W);
            else           scatterP2<<<dim3(32, 25, NBB), 256, 0, stream>>>(x0, xp, W);
            repack_w<<<576, 256, 0, stream>>>(conv_w, wb);

            conv_mfma<<<dim3(8, NBB * 25), 256, 0, stream>>>(
                xp, wb, (pass == 0) ? buffer : (const float*)out, out, bb0);
        }
    }
}

// Round 5
// 1462.333 us; speedup vs baseline: 2.9477x; 1.1408x over previous
//
#include <hip/hip_runtime.h>
#include <math.h>
#include <stdint.h>

typedef __attribute__((ext_vector_type(8))) short bf16x8;
typedef __attribute__((ext_vector_type(4))) float f32x4;

static __device__ __forceinline__ unsigned short f2bf(float f) {
    unsigned u = __builtin_bit_cast(unsigned, f);
    unsigned r = u + 0x7fffu + ((u >> 16) & 1u);   // RNE
    return (unsigned short)(r >> 16);
}

// ---------------------------------------------------------------------------
// gather pass1: x0[t'][cc] = src[bb][cc][u*5+v][y][x], l=u*32+y, col=lb*160+v*32+x
__global__ __launch_bounds__(256) void gather1(const float* __restrict__ src, float* __restrict__ x0,
                                               int W, int bb0) {
    int cct = blockIdx.x & 3, y = blockIdx.x >> 2;
    int n = blockIdx.y; int u = n / 5, v = n % 5;
    int lb = blockIdx.z, bb = bb0 + lb;
    __shared__ float tile[32][33];
    int tx = threadIdx.x & 31, tg = threadIdx.x >> 5;
    const float* s = src + (((size_t)(bb * 128 + cct * 32) * 25 + n) * 32 + y) * 32;
    #pragma unroll
    for (int i = 0; i < 4; i++) {
        int cl = tg + 8 * i;
        tile[cl][tx] = s[(size_t)cl * 25600 + tx];      // [cc_local][x]
    }
    __syncthreads();
    float* d = x0 + ((size_t)(u * 32 + y) * W + lb * 160 + v * 32) * 128 + cct * 32;
    #pragma unroll
    for (int i = 0; i < 4; i++) {
        int xx = tg + 8 * i;
        d[(size_t)xx * 128 + tx] = tile[tx][xx];
    }
}

// gather pass2: x0[t'][cc] = src[bb][cc][u*5+v][y][x], l=v*32+x, col=lb*160+u*32+y
__global__ __launch_bounds__(256) void gather2(const float* __restrict__ src, float* __restrict__ x0,
                                               int W, int bb0) {
    int cct = blockIdx.x & 3, x = blockIdx.x >> 2;
    int n = blockIdx.y; int u = n / 5, v = n % 5;
    int lb = blockIdx.z, bb = bb0 + lb;
    __shared__ float tile[32][33];
    int tx = threadIdx.x & 31, tg = threadIdx.x >> 5;
    const float* s = src + (((size_t)(bb * 128 + cct * 32) * 25 + n) * 32) * 32 + x;
    #pragma unroll
    for (int i = 0; i < 4; i++) {
        int cl = tg + 8 * i;
        tile[cl][tx] = s[(size_t)cl * 25600 + tx * 32];  // [cc_local][y]
    }
    __syncthreads();
    float* d = x0 + ((size_t)(v * 32 + x) * W + lb * 160 + u * 32) * 128 + cct * 32;
    #pragma unroll
    for (int i = 0; i < 4; i++) {
        int yy = tg + 8 * i;
        d[(size_t)yy * 128 + tx] = tile[tx][yy];
    }
}

// ---------------------------------------------------------------------------
// scatterP pass1: xp[(lb*25 + u*5+v)][y*32+x][cc] (bf16) = ot[t][cc]
__global__ __launch_bounds__(256) void scatterP1(const float* __restrict__ ot,
                                                 unsigned short* __restrict__ xp, int W) {
    int y = blockIdx.x, n = blockIdx.y, lb = blockIdx.z;
    int u = n / 5, v = n % 5;
    int x = threadIdx.x >> 3, cg = threadIdx.x & 7;
    size_t t = (size_t)(u * 32 + y) * W + lb * 160 + v * 32 + x;
    const float4* s = (const float4*)(ot + t * 128 + cg * 16);
    float4 a = s[0], b = s[1], c = s[2], d = s[3];
    ushort4 o0, o1, o2, o3;
    o0.x = f2bf(a.x); o0.y = f2bf(a.y); o0.z = f2bf(a.z); o0.w = f2bf(a.w);
    o1.x = f2bf(b.x); o1.y = f2bf(b.y); o1.z = f2bf(b.z); o1.w = f2bf(b.w);
    o2.x = f2bf(c.x); o2.y = f2bf(c.y); o2.z = f2bf(c.z); o2.w = f2bf(c.w);
    o3.x = f2bf(d.x); o3.y = f2bf(d.y); o3.z = f2bf(d.z); o3.w = f2bf(d.w);
    ushort4* dp = (ushort4*)(xp + (((size_t)(lb * 25 + n) * 1024 + y * 32 + x) * 128 + cg * 16));
    dp[0] = o0; dp[1] = o1; dp[2] = o2; dp[3] = o3;
}

// scatterP pass2
__global__ __launch_bounds__(256) void scatterP2(const float* __restrict__ ot,
                                                 unsigned short* __restrict__ xp, int W) {
    int y = blockIdx.x, n = blockIdx.y, lb = blockIdx.z;
    int u = n / 5, v = n % 5;
    int x = threadIdx.x >> 3, cg = threadIdx.x & 7;
    size_t t = (size_t)(v * 32 + x) * W + lb * 160 + u * 32 + y;
    const float4* s = (const float4*)(ot + t * 128 + cg * 16);
    float4 a = s[0], b = s[1], c = s[2], d = s[3];
    ushort4 o0, o1, o2, o3;
    o0.x = f2bf(a.x); o0.y = f2bf(a.y); o0.z = f2bf(a.z); o0.w = f2bf(a.w);
    o1.x = f2bf(b.x); o1.y = f2bf(b.y); o1.z = f2bf(b.z); o1.w = f2bf(b.w);
    o2.x = f2bf(c.x); o2.y = f2bf(c.y); o2.z = f2bf(c.z); o2.w = f2bf(c.w);
    o3.x = f2bf(d.x); o3.y = f2bf(d.y); o3.z = f2bf(d.z); o3.w = f2bf(d.w);
    ushort4* dp = (ushort4*)(xp + (((size_t)(lb * 25 + n) * 1024 + y * 32 + x) * 128 + cg * 16));
    dp[0] = o0; dp[1] = o1; dp[2] = o2; dp[3] = o3;
}

// ---------------------------------------------------------------------------
// conv weight repack: conv_w[co][ci][tap(9)] f32 -> wb[tap][co][ci] bf16
__global__ __launch_bounds__(256) void repack_w(const float* __restrict__ cw,
                                                unsigned short* __restrict__ wb) {
    int g = blockIdx.x * 256 + threadIdx.x;     // 147456 total
    int co = g / 1152;
    int rem = g - co * 1152;
    int ci = rem / 9, tap = rem - ci * 9;
    wb[((size_t)tap * 128 + co) * 128 + ci] = f2bf(cw[g]);
}

// ---------------------------------------------------------------------------
// LayerNorm over E=256, one wave per token, 4 tokens per block
__global__ __launch_bounds__(256) void ln_kernel(const float* __restrict__ in, float* __restrict__ out,
                                                 const float* __restrict__ w, const float* __restrict__ b) {
    int tok = blockIdx.x * 4 + (threadIdx.x >> 6);
    int lane = threadIdx.x & 63;
    const float4 v4 = ((const float4*)(in + (size_t)tok * 256))[lane];
    float s = v4.x + v4.y + v4.z + v4.w;
    #pragma unroll
    for (int off = 32; off > 0; off >>= 1) s += __shfl_xor(s, off);
    float mu = s * (1.0f / 256.0f);
    float dx = v4.x - mu, dy = v4.y - mu, dz = v4.z - mu, dw = v4.w - mu;
    float vs = dx * dx + dy * dy + dz * dz + dw * dw;
    #pragma unroll
    for (int off = 32; off > 0; off >>= 1) vs += __shfl_xor(vs, off);
    float inv = rsqrtf(vs * (1.0f / 256.0f) + 1e-5f);
    float4 wv = ((const float4*)w)[lane];
    float4 bv = ((const float4*)b)[lane];
    float4 o4;
    o4.x = dx * inv * wv.x + bv.x;
    o4.y = dy * inv * wv.y + bv.y;
    o4.z = dz * inv * wv.z + bv.z;
    o4.w = dw * inv * wv.w + bv.w;
    ((float4*)(out + (size_t)tok * 256))[lane] = o4;
}

// ---------------------------------------------------------------------------
// bf16-MFMA GEMM: Y[M,N] = X[M,K] @ Wt[N,K]^T (+R) (relu?)  128x128, BK=64
// obf16: write output as bf16 (token-major) instead of f32.
__global__ __launch_bounds__(256) void gemm_mfma(const float* __restrict__ X,
                                                 const float* __restrict__ Wt,
                                                 void* __restrict__ Yv, const float* __restrict__ R,
                                                 int N, int K, int relu, int obf16) {
    __shared__ short As[128 * 64];
    __shared__ short Bs[128 * 64];
    const int bm = blockIdx.x * 128, bn = blockIdx.y * 128;
    const int tid = threadIdx.x;
    const int lane = tid & 63, w = tid >> 6;
    const int wm = (w >> 1) * 64, wn = (w & 1) * 64;
    const int lr = lane & 15, lq = lane >> 4;
    f32x4 acc[4][4];
    #pragma unroll
    for (int m = 0; m < 4; m++)
        #pragma unroll
        for (int n = 0; n < 4; n++)
            acc[m][n] = (f32x4){0.f, 0.f, 0.f, 0.f};

    for (int k0 = 0; k0 < K; k0 += 64) {
        #pragma unroll
        for (int i = 0; i < 8; i++) {
            int id = tid + 256 * i;              // 0..2047
            int row = id >> 4, cg = id & 15;     // row 0..127, col-group of 4
            float4 va = *(const float4*)(X  + (size_t)(bm + row) * K + k0 + cg * 4);
            float4 vb = *(const float4*)(Wt + (size_t)(bn + row) * K + k0 + cg * 4);
            ushort4 ba, bb;
            ba.x = f2bf(va.x); ba.y = f2bf(va.y); ba.z = f2bf(va.z); ba.w = f2bf(va.w);
            bb.x = f2bf(vb.x); bb.y = f2bf(vb.y); bb.z = f2bf(vb.z); bb.w = f2bf(vb.w);
            int boff = row * 128 + ((cg * 8) ^ ((row & 7) << 4));
            *(ushort4*)((char*)As + boff) = ba;
            *(ushort4*)((char*)Bs + boff) = bb;
        }
        __syncthreads();
        #pragma unroll
        for (int ks = 0; ks < 2; ks++) {
            bf16x8 af[4], bf[4];
            #pragma unroll
            for (int m = 0; m < 4; m++) {
                int row = wm + m * 16 + lr;
                int boff = row * 128 + ((ks * 64 + lq * 16) ^ ((row & 7) << 4));
                af[m] = *(const bf16x8*)((const char*)As + boff);
            }
            #pragma unroll
            for (int n = 0; n < 4; n++) {
                int row = wn + n * 16 + lr;
                int boff = row * 128 + ((ks * 64 + lq * 16) ^ ((row & 7) << 4));
                bf[n] = *(const bf16x8*)((const char*)Bs + boff);
            }
            #pragma unroll
            for (int m = 0; m < 4; m++)
                #pragma unroll
                for (int n = 0; n < 4; n++)
                    acc[m][n] = __builtin_amdgcn_mfma_f32_16x16x32_bf16(af[m], bf[n], acc[m][n], 0, 0, 0);
        }
        __syncthreads();
    }
    #pragma unroll
    for (int m = 0; m < 4; m++) {
        int row0 = bm + wm + m * 16 + lq * 4;
        #pragma unroll
        for (int r = 0; r < 4; r++) {
            size_t rowoff = (size_t)(row0 + r) * N;
            #pragma unroll
            for (int n = 0; n < 4; n++) {
                int col = bn + wn + n * 16 + lr;
                float val = acc[m][n][r];
                if (R) val += R[rowoff + col];
                if (relu) val = fmaxf(val, 0.0f);
                if (obf16) ((unsigned short*)Yv)[rowoff + col] = f2bf(val);
                else       ((float*)Yv)[rowoff + col] = val;
            }
        }
    }
}

// ---------------------------------------------------------------------------
// V transpose: Vtok[t][256] bf16 -> Vt[h][col][d(32)][l(160)] bf16
__global__ __launch_bounds__(256) void vtrans(const unsigned short* __restrict__ vtok,
                                              unsigned short* __restrict__ vt, int W) {
    const int col = blockIdx.x, h = blockIdx.y;
    __shared__ unsigned short t[160][34];
    const int tid = threadIdx.x;
    for (int i = tid; i < 160 * 16; i += 256) {
        int l = i >> 4, dp = i & 15;
        unsigned v = *(const unsigned*)(vtok + ((size_t)l * W + col) * 256 + h * 32 + dp * 2);
        *(unsigned*)&t[l][dp * 2] = v;
    }
    __syncthreads();
    unsigned short* dst = vt + (((size_t)h * W + col) * 32) * 160;
    for (int i = tid; i < 32 * 160; i += 256) {
        int d = i / 160, l = i - d * 160;
        dst[i] = t[l][d];
    }
}

// ---------------------------------------------------------------------------
// MFMA attention, one wave per (col, head). L=160, hd=32.
// S^T tile = mfma(A=K rows, B=Q rows) -> D[row=key][col(lane&15)=query].
// Softmax in-lane (40 vals) + shfl_xor(16,32). P^T -> LDS -> B-frag for PV.
// O^T = mfma(A=V^T rows, B=P^T) -> D[row=d][col=query].
__global__ __launch_bounds__(64) void attn_mfma(const unsigned short* __restrict__ qk,  // [t][512] bf16
                                                const unsigned short* __restrict__ vt,  // [h][col][32][160] bf16
                                                float* __restrict__ o, int W) {
    const int col = blockIdx.x;
    const int h = blockIdx.y;
    const int lane = threadIdx.x;
    const int lr = lane & 15, lq = lane >> 4;
    __shared__ __align__(16) unsigned short P_lds[16][168];   // [q][k], pad->2-way max

    // K A-frags (key = m*16+lr, dim = lq*8..+7), cached for all 10 q-tiles
    bf16x8 kf[10];
    #pragma unroll
    for (int m = 0; m < 10; m++) {
        size_t t = (size_t)(m * 16 + lr) * W + col;
        kf[m] = *(const bf16x8*)(qk + t * 512 + 256 + h * 32 + lq * 8);
    }
    // V^T A-frags (row d = md*16+lr, k chunk c)
    const unsigned short* vbase = vt + (((size_t)h * W + col) * 32) * 160;
    bf16x8 vf[2][5];
    #pragma unroll
    for (int md = 0; md < 2; md++)
        #pragma unroll
        for (int c = 0; c < 5; c++)
            vf[md][c] = *(const bf16x8*)(vbase + (size_t)(md * 16 + lr) * 160 + c * 32 + lq * 8);

    const float scale = 0.17677669529663687f;   // 1/sqrt(32)
    for (int n = 0; n < 10; n++) {
        const int q = n * 16 + lr;
        bf16x8 qf = *(const bf16x8*)(qk + ((size_t)q * W + col) * 512 + h * 32 + lq * 8);
        f32x4 p[10];
        #pragma unroll
        for (int m = 0; m < 10; m++)
            p[m] = __builtin_amdgcn_mfma_f32_16x16x32_bf16(kf[m], qf, (f32x4){0.f,0.f,0.f,0.f}, 0, 0, 0);
        // mask (|yk-yq|<=5, all uk allowed) + max.  yk = (m&1)*16 + lq*4 + r
        const int b = lq * 4 - ((n & 1) * 16 + lr);
        float mx = -1e30f;
        #pragma unroll
        for (int m = 0; m < 10; m++) {
            #pragma unroll
            for (int r = 0; r < 4; r++) {
                int dd = b + (m & 1) * 16 + r;          // yk - yq
                float s = ((unsigned)(dd + 5) <= 10u) ? p[m][r] : -1e30f;
                p[m][r] = s;
                mx = fmaxf(mx, s);
            }
        }
        mx = fmaxf(mx, __shfl_xor(mx, 16));
        mx = fmaxf(mx, __shfl_xor(mx, 32));
        float sum = 0.f;
        #pragma unroll
        for (int m = 0; m < 10; m++) {
            #pragma unroll
            for (int r = 0; r < 4; r++) {
                float e = __expf((p[m][r] - mx) * scale);
                p[m][r] = e;
                sum += e;
            }
        }
        sum += __shfl_xor(sum, 16);
        sum += __shfl_xor(sum, 32);
        // write P^T (unnormalized) to LDS: P_lds[q=lr][k = m*16 + lq*4 + r]
        #pragma unroll
        for (int m = 0; m < 10; m++) {
            ushort4 pk;
            pk.x = f2bf(p[m][0]); pk.y = f2bf(p[m][1]);
            pk.z = f2bf(p[m][2]); pk.w = f2bf(p[m][3]);
            *(ushort4*)&P_lds[lr][m * 16 + lq * 4] = pk;
        }
        // PV (single wave: program order + lgkmcnt keeps LDS consistent)
        f32x4 oa0 = (f32x4){0.f,0.f,0.f,0.f}, oa1 = (f32x4){0.f,0.f,0.f,0.f};
        #pragma unroll
        for (int c = 0; c < 5; c++) {
            bf16x8 pf = *(const bf16x8*)&P_lds[lr][c * 32 + lq * 8];
            oa0 = __builtin_amdgcn_mfma_f32_16x16x32_bf16(vf[0][c], pf, oa0, 0, 0, 0);
            oa1 = __builtin_amdgcn_mfma_f32_16x16x32_bf16(vf[1][c], pf, oa1, 0, 0, 0);
        }
        const float inv = 1.0f / sum;
        float* op = o + ((size_t)q * W + col) * 256 + h * 32;
        float4 s0, s1;
        s0.x = oa0[0] * inv; s0.y = oa0[1] * inv; s0.z = oa0[2] * inv; s0.w = oa0[3] * inv;
        s1.x = oa1[0] * inv; s1.y = oa1[1] * inv; s1.z = oa1[2] * inv; s1.w = oa1[3] * inv;
        *(float4*)(op + lq * 4)      = s0;       // d = 0*16 + lq*4 + r
        *(float4*)(op + 16 + lq * 4) = s1;       // d = 1*16 + lq*4 + r
    }
}

// ---------------------------------------------------------------------------
// conv as implicit MFMA GEMM (verified round 3)
__global__ __launch_bounds__(256) void conv_mfma(const unsigned short* __restrict__ xp,
                                                 const unsigned short* __restrict__ wb,
                                                 const float* __restrict__ res,
                                                 float* __restrict__ out, int bb0) {
    const int ptile = blockIdx.x;
    const int slice = blockIdx.y;
    const int lb = slice / 25, n = slice % 25;
    const int bb = bb0 + lb;
    const int y0 = ptile * 4;
    __shared__ unsigned short As[128 * 64];
    __shared__ unsigned short Bs[128 * 64];
    const int tid = threadIdx.x;
    const int lane = tid & 63, w = tid >> 6;
    const int wm = (w >> 1) * 64;
    const int wn = (w & 1) * 64;
    const int lr = lane & 15, lq = lane >> 4;
    const unsigned short* xs = xp + (size_t)slice * 1024 * 128;
    f32x4 acc[4][4];
    #pragma unroll
    for (int m = 0; m < 4; m++)
        #pragma unroll
        for (int nn = 0; nn < 4; nn++)
            acc[m][nn] = (f32x4){0.f, 0.f, 0.f, 0.f};

    for (int tap = 0; tap < 9; tap++) {
        const int dy = tap / 3 - 1, dx = tap % 3 - 1;
        for (int c0 = 0; c0 < 128; c0 += 64) {
            #pragma unroll
            for (int i = 0; i < 4; i++) {
                int id = tid + 256 * i;
                int row = id >> 3, cg = id & 7;
                int py = y0 + (row >> 5) + dy;
                int px = (row & 31) + dx;
                uint4 v = {0u, 0u, 0u, 0u};
                if ((unsigned)py < 32u && (unsigned)px < 32u)
                    v = *(const uint4*)(xs + ((size_t)(py * 32 + px) * 128 + c0 + cg * 8));
                int boff = row * 128 + ((cg * 16) ^ ((row & 7) << 4));
                *(uint4*)((char*)As + boff) = v;
            }
            #pragma unroll
            for (int i = 0; i < 4; i++) {
                int id = tid + 256 * i;
                int row = id >> 3, cg = id & 7;
                uint4 v = *(const uint4*)(wb + (((size_t)tap * 128 + row) * 128 + c0 + cg * 8));
                int boff = row * 128 + ((cg * 16) ^ ((row & 7) << 4));
                *(uint4*)((char*)Bs + boff) = v;
            }
            __syncthreads();
            #pragma unroll
            for (int ks = 0; ks < 2; ks++) {
                bf16x8 wf[4], xf[4];
                #pragma unroll
                for (int m = 0; m < 4; m++) {
                    int row = wm + m * 16 + lr;
                    int boff = row * 128 + ((ks * 64 + lq * 16) ^ ((row & 7) << 4));
                    wf[m] = *(const bf16x8*)((const char*)Bs + boff);
                }
                #pragma unroll
                for (int nn = 0; nn < 4; nn++) {
                    int row = wn + nn * 16 + lr;
                    int boff = row * 128 + ((ks * 64 + lq * 16) ^ ((row & 7) << 4));
                    xf[nn] = *(const bf16x8*)((const char*)As + boff);
                }
                #pragma unroll
                for (int m = 0; m < 4; m++)
                    #pragma unroll
                    for (int nn = 0; nn < 4; nn++)
                        acc[m][nn] = __builtin_amdgcn_mfma_f32_16x16x32_bf16(wf[m], xf[nn], acc[m][nn], 0, 0, 0);
            }
            __syncthreads();
        }
    }
    #pragma unroll
    for (int m = 0; m < 4; m++) {
        int co0 = wm + m * 16 + lq * 4;
        #pragma unroll
        for (int r = 0; r < 4; r++) {
            size_t rowoff = (((size_t)(bb * 128 + co0 + r) * 25 + n) * 1024) + ptile * 128;
            #pragma unroll
            for (int nn = 0; nn < 4; nn++) {
                int pix = wn + nn * 16 + lr;
                out[rowoff + pix] = acc[m][nn][r] + res[rowoff + pix];
            }
        }
    }
}

// ---------------------------------------------------------------------------
extern "C" void kernel_launch(void* const* d_in, const int* in_sizes, int n_in,
                              void* d_out, int out_size, void* d_ws, size_t ws_size,
                              hipStream_t stream) {
    (void)in_sizes; (void)n_in; (void)out_size;
    const float* buffer     = (const float*)d_in[0];
    const float* Win        = (const float*)d_in[1];
    const float* ln_w       = (const float*)d_in[2];
    const float* ln_b       = (const float*)d_in[3];
    const float* in_proj    = (const float*)d_in[4];
    const float* attn_out_w = (const float*)d_in[5];
    const float* ffn_ln_w   = (const float*)d_in[6];
    const float* ffn_ln_b   = (const float*)d_in[7];
    const float* ff1        = (const float*)d_in[8];
    const float* ff2        = (const float*)d_in[9];
    const float* Wout       = (const float*)d_in[10];
    const float* conv_w     = (const float*)d_in[11];
    float* out = (float*)d_out;
    float* ws  = (float*)d_ws;

    int NBB = (ws_size >= (size_t)2 * 25600 * 1408 * 4) ? 2 : 1;
    const int W = NBB * 160;
    const size_t T = (size_t)NBB * 25600;

    float* x0  = ws;                  // T*128
    float* A   = ws + T * 128;        // T*256  tok (residual stream)
    float* B   = ws + T * 384;        // T*256  tn / tn2
    float* C   = ws + T * 640;        // T*512  region: QKtok/Vtok/Vt -> ffn hidden -> xp
    float* D   = ws + T * 1152;       // T*256  attn out
    unsigned short* QKtok = (unsigned short*)C;              // T*512 bf16
    unsigned short* Vtok  = (unsigned short*)(C + T * 256);  // T*256 bf16
    unsigned short* Vt    = (unsigned short*)(C + T * 384);  // T*256 bf16
    unsigned short* xp = (unsigned short*)C;                 // T*128 bf16 (after hidden dead)
    unsigned short* wb = (unsigned short*)(ws + T * 704);    // 147456 bf16

    const int GM = (int)(T / 128);

    for (int pass = 0; pass < 2; pass++) {
        const float* src = (pass == 0) ? buffer : out;
        for (int bb0 = 0; bb0 < 2; bb0 += NBB) {
            if (pass == 0) gather1<<<dim3(128, 25, NBB), 256, 0, stream>>>(src, x0, W, bb0);
            else           gather2<<<dim3(128, 25, NBB), 256, 0, stream>>>(src, x0, W, bb0);

            // tok = x0 @ Win^T                  (K=128 -> N=256)
            gemm_mfma<<<dim3(GM, 2), 256, 0, stream>>>(x0, Win, A, nullptr, 256, 128, 0, 0);
            ln_kernel<<<(int)(T / 4), 256, 0, stream>>>(A, B, ln_w, ln_b);
            // qk(bf16) = tn @ [Wq;Wk]^T         (N=512)
            gemm_mfma<<<dim3(GM, 4), 256, 0, stream>>>(B, in_proj, QKtok, nullptr, 512, 256, 0, 1);
            // v(bf16) = tok @ Wv^T
            gemm_mfma<<<dim3(GM, 2), 256, 0, stream>>>(A, in_proj + (size_t)512 * 256, Vtok, nullptr, 256, 256, 0, 1);
            vtrans<<<dim3(W, 8), 256, 0, stream>>>(Vtok, Vt, W);
            attn_mfma<<<dim3(W, 8), 64, 0, stream>>>(QKtok, Vt, D, W);
            // tok += ob @ attn_out_w^T
            gemm_mfma<<<dim3(GM, 2), 256, 0, stream>>>(D, attn_out_w, A, A, 256, 256, 0, 0);
            ln_kernel<<<(int)(T / 4), 256, 0, stream>>>(A, B, ffn_ln_w, ffn_ln_b);
            // hidden = relu(tn2 @ ff1^T)        (N=512)
            gemm_mfma<<<dim3(GM, 4), 256, 0, stream>>>(B, ff1, C, nullptr, 512, 256, 1, 0);
            // tok += hidden @ ff2^T             (K=512)
            gemm_mfma<<<dim3(GM, 2), 256, 0, stream>>>(C, ff2, A, A, 256, 512, 0, 0);
            // ot = tok @ Wout^T                 (N=128) -> x0
            gemm_mfma<<<dim3(GM, 1), 256, 0, stream>>>(A, Wout, x0, nullptr, 128, 256, 0, 0);

            if (pass == 0) scatterP1<<<dim3(32, 25, NBB), 256, 0, stream>>>(x0, xp, W);
            else           scatterP2<<<dim3(32, 25, NBB), 256, 0, stream>>>(x0, xp, W);
            repack_w<<<576, 256, 0, stream>>>(conv_w, wb);

            conv_mfma<<<dim3(8, NBB * 25), 256, 0, stream>>>(
                xp, wb, (pass == 0) ? buffer : (const float*)out, out, bb0);
        }
    }
}

// Round 6
// 1415.401 us; speedup vs baseline: 3.0454x; 1.0332x over previous
//
#include <hip/hip_runtime.h>
#include <math.h>
#include <stdint.h>

typedef __attribute__((ext_vector_type(8))) short bf16x8;
typedef __attribute__((ext_vector_type(4))) float f32x4;

static __device__ __forceinline__ unsigned short f2bf(float f) {
    unsigned u = __builtin_bit_cast(unsigned, f);
    unsigned r = u + 0x7fffu + ((u >> 16) & 1u);   // RNE
    return (unsigned short)(r >> 16);
}

// ---------------------------------------------------------------------------
// gather pass1: x0b[t'][cc] (bf16) = src[bb][cc][u*5+v][y][x]
__global__ __launch_bounds__(256) void gather1(const float* __restrict__ src,
                                               unsigned short* __restrict__ x0, int W, int bb0) {
    int cct = blockIdx.x & 3, y = blockIdx.x >> 2;
    int n = blockIdx.y; int u = n / 5, v = n % 5;
    int lb = blockIdx.z, bb = bb0 + lb;
    __shared__ float tile[32][33];
    int tx = threadIdx.x & 31, tg = threadIdx.x >> 5;
    const float* s = src + (((size_t)(bb * 128 + cct * 32) * 25 + n) * 32 + y) * 32;
    #pragma unroll
    for (int i = 0; i < 4; i++) {
        int cl = tg + 8 * i;
        tile[cl][tx] = s[(size_t)cl * 25600 + tx];
    }
    __syncthreads();
    unsigned short* d = x0 + ((size_t)(u * 32 + y) * W + lb * 160 + v * 32) * 128 + cct * 32;
    #pragma unroll
    for (int i = 0; i < 4; i++) {
        int xx = tg + 8 * i;
        d[(size_t)xx * 128 + tx] = f2bf(tile[tx][xx]);
    }
}

// gather pass2
__global__ __launch_bounds__(256) void gather2(const float* __restrict__ src,
                                               unsigned short* __restrict__ x0, int W, int bb0) {
    int cct = blockIdx.x & 3, x = blockIdx.x >> 2;
    int n = blockIdx.y; int u = n / 5, v = n % 5;
    int lb = blockIdx.z, bb = bb0 + lb;
    __shared__ float tile[32][33];
    int tx = threadIdx.x & 31, tg = threadIdx.x >> 5;
    const float* s = src + (((size_t)(bb * 128 + cct * 32) * 25 + n) * 32) * 32 + x;
    #pragma unroll
    for (int i = 0; i < 4; i++) {
        int cl = tg + 8 * i;
        tile[cl][tx] = s[(size_t)cl * 25600 + tx * 32];
    }
    __syncthreads();
    unsigned short* d = x0 + ((size_t)(v * 32 + x) * W + lb * 160 + u * 32) * 128 + cct * 32;
    #pragma unroll
    for (int i = 0; i < 4; i++) {
        int yy = tg + 8 * i;
        d[(size_t)yy * 128 + tx] = f2bf(tile[tx][yy]);
    }
}

// ---------------------------------------------------------------------------
// scatterP: bf16 token-major -> bf16 pixel-major [slice][pix][ci]
__global__ __launch_bounds__(256) void scatterP1(const unsigned short* __restrict__ ot,
                                                 unsigned short* __restrict__ xp, int W) {
    int y = blockIdx.x, n = blockIdx.y, lb = blockIdx.z;
    int u = n / 5, v = n % 5;
    int x = threadIdx.x >> 3, cg = threadIdx.x & 7;
    size_t t = (size_t)(u * 32 + y) * W + lb * 160 + v * 32 + x;
    const uint4* s = (const uint4*)(ot + t * 128 + cg * 16);
    uint4 a = s[0], b = s[1];
    uint4* dp = (uint4*)(xp + (((size_t)(lb * 25 + n) * 1024 + y * 32 + x) * 128 + cg * 16));
    dp[0] = a; dp[1] = b;
}

__global__ __launch_bounds__(256) void scatterP2(const unsigned short* __restrict__ ot,
                                                 unsigned short* __restrict__ xp, int W) {
    int y = blockIdx.x, n = blockIdx.y, lb = blockIdx.z;
    int u = n / 5, v = n % 5;
    int x = threadIdx.x >> 3, cg = threadIdx.x & 7;
    size_t t = (size_t)(v * 32 + x) * W + lb * 160 + u * 32 + y;
    const uint4* s = (const uint4*)(ot + t * 128 + cg * 16);
    uint4 a = s[0], b = s[1];
    uint4* dp = (uint4*)(xp + (((size_t)(lb * 25 + n) * 1024 + y * 32 + x) * 128 + cg * 16));
    dp[0] = a; dp[1] = b;
}

// ---------------------------------------------------------------------------
// conv weight repack: conv_w[co][ci][tap(9)] f32 -> wb[tap][co][ci] bf16
__global__ __launch_bounds__(256) void repack_w(const float* __restrict__ cw,
                                                unsigned short* __restrict__ wb) {
    int g = blockIdx.x * 256 + threadIdx.x;
    int co = g / 1152;
    int rem = g - co * 1152;
    int ci = rem / 9, tap = rem - ci * 9;
    wb[((size_t)tap * 128 + co) * 128 + ci] = f2bf(cw[g]);
}

// GEMM weights -> one bf16 buffer (layout preserved [N][K])
__global__ __launch_bounds__(256) void conv_weights(const float* __restrict__ Win,
                                                    const float* __restrict__ in_proj,
                                                    const float* __restrict__ attn_out_w,
                                                    const float* __restrict__ ff1,
                                                    const float* __restrict__ ff2,
                                                    const float* __restrict__ Wout,
                                                    unsigned short* __restrict__ wg) {
    int g = blockIdx.x * 256 + threadIdx.x;      // 589824 total
    float v;
    if      (g < 32768)  v = Win[g];
    else if (g < 229376) v = in_proj[g - 32768];
    else if (g < 294912) v = attn_out_w[g - 229376];
    else if (g < 425984) v = ff1[g - 294912];
    else if (g < 557056) v = ff2[g - 425984];
    else                 v = Wout[g - 557056];
    wg[g] = f2bf(v);
}

// ---------------------------------------------------------------------------
// LayerNorm over E=256, f32 in -> bf16 out
__global__ __launch_bounds__(256) void ln_kernel(const float* __restrict__ in,
                                                 unsigned short* __restrict__ out,
                                                 const float* __restrict__ w, const float* __restrict__ b) {
    int tok = blockIdx.x * 4 + (threadIdx.x >> 6);
    int lane = threadIdx.x & 63;
    const float4 v4 = ((const float4*)(in + (size_t)tok * 256))[lane];
    float s = v4.x + v4.y + v4.z + v4.w;
    #pragma unroll
    for (int off = 32; off > 0; off >>= 1) s += __shfl_xor(s, off);
    float mu = s * (1.0f / 256.0f);
    float dx = v4.x - mu, dy = v4.y - mu, dz = v4.z - mu, dw = v4.w - mu;
    float vs = dx * dx + dy * dy + dz * dz + dw * dw;
    #pragma unroll
    for (int off = 32; off > 0; off >>= 1) vs += __shfl_xor(vs, off);
    float inv = rsqrtf(vs * (1.0f / 256.0f) + 1e-5f);
    float4 wv = ((const float4*)w)[lane];
    float4 bv = ((const float4*)b)[lane];
    ushort4 o4;
    o4.x = f2bf(dx * inv * wv.x + bv.x);
    o4.y = f2bf(dy * inv * wv.y + bv.y);
    o4.z = f2bf(dz * inv * wv.z + bv.z);
    o4.w = f2bf(dw * inv * wv.w + bv.w);
    *(ushort4*)(out + (size_t)tok * 256 + lane * 4) = o4;
}

// ---------------------------------------------------------------------------
// bf16-in MFMA GEMM with register prefetch.  Y = X[M,K](bf16) @ Wt[N,K](bf16)^T
// (+R f32) (relu?) -> Yf (f32) and/or Yb (bf16).  128x128 tile, BK=64.
__global__ __launch_bounds__(256) void gemm_bf16(const unsigned short* __restrict__ X,
                                                 const unsigned short* __restrict__ Wt,
                                                 float* __restrict__ Yf,
                                                 unsigned short* __restrict__ Yb,
                                                 const float* __restrict__ R,
                                                 int N, int K, int relu) {
    __shared__ unsigned short As[128 * 64];
    __shared__ unsigned short Bs[128 * 64];
    const int bm = blockIdx.x * 128, bn = blockIdx.y * 128;
    const int tid = threadIdx.x;
    const int lane = tid & 63, w = tid >> 6;
    const int wm = (w >> 1) * 64, wn = (w & 1) * 64;
    const int lr = lane & 15, lq = lane >> 4;
    f32x4 acc[4][4];
    #pragma unroll
    for (int m = 0; m < 4; m++)
        #pragma unroll
        for (int n = 0; n < 4; n++)
            acc[m][n] = (f32x4){0.f, 0.f, 0.f, 0.f};

    uint4 ra[4], rb[4];
    const int srow = tid >> 3, scg = tid & 7;    // row += 32 per i
    #pragma unroll
    for (int i = 0; i < 4; i++) {
        int row = srow + i * 32;
        ra[i] = *(const uint4*)(X  + (size_t)(bm + row) * K + scg * 8);
        rb[i] = *(const uint4*)(Wt + (size_t)(bn + row) * K + scg * 8);
    }

    for (int k0 = 0;;) {
        #pragma unroll
        for (int i = 0; i < 4; i++) {
            int row = srow + i * 32;
            int boff = row * 128 + ((scg * 16) ^ ((row & 7) << 4));
            *(uint4*)((char*)As + boff) = ra[i];
            *(uint4*)((char*)Bs + boff) = rb[i];
        }
        __syncthreads();
        const bool more = (k0 + 64) < K;
        if (more) {
            #pragma unroll
            for (int i = 0; i < 4; i++) {
                int row = srow + i * 32;
                ra[i] = *(const uint4*)(X  + (size_t)(bm + row) * K + k0 + 64 + scg * 8);
                rb[i] = *(const uint4*)(Wt + (size_t)(bn + row) * K + k0 + 64 + scg * 8);
            }
        }
        #pragma unroll
        for (int ks = 0; ks < 2; ks++) {
            bf16x8 af[4], bf[4];
            #pragma unroll
            for (int m = 0; m < 4; m++) {
                int row = wm + m * 16 + lr;
                int boff = row * 128 + ((ks * 64 + lq * 16) ^ ((row & 7) << 4));
                af[m] = *(const bf16x8*)((const char*)As + boff);
            }
            #pragma unroll
            for (int n = 0; n < 4; n++) {
                int row = wn + n * 16 + lr;
                int boff = row * 128 + ((ks * 64 + lq * 16) ^ ((row & 7) << 4));
                bf[n] = *(const bf16x8*)((const char*)Bs + boff);
            }
            #pragma unroll
            for (int m = 0; m < 4; m++)
                #pragma unroll
                for (int n = 0; n < 4; n++)
                    acc[m][n] = __builtin_amdgcn_mfma_f32_16x16x32_bf16(af[m], bf[n], acc[m][n], 0, 0, 0);
        }
        __syncthreads();
        k0 += 64;
        if (!more) break;
    }
    #pragma unroll
    for (int m = 0; m < 4; m++) {
        int row0 = bm + wm + m * 16 + lq * 4;
        #pragma unroll
        for (int r = 0; r < 4; r++) {
            size_t rowoff = (size_t)(row0 + r) * N;
            #pragma unroll
            for (int n = 0; n < 4; n++) {
                int col = bn + wn + n * 16 + lr;
                float val = acc[m][n][r];
                if (R) val += R[rowoff + col];
                if (relu) val = fmaxf(val, 0.0f);
                if (Yf) Yf[rowoff + col] = val;
                if (Yb) Yb[rowoff + col] = f2bf(val);
            }
        }
    }
}

// ---------------------------------------------------------------------------
// V transpose: Vtok[t][256] bf16 -> Vt[h][col][d(32)][l(160)] bf16
__global__ __launch_bounds__(256) void vtrans(const unsigned short* __restrict__ vtok,
                                              unsigned short* __restrict__ vt, int W) {
    const int col = blockIdx.x, h = blockIdx.y;
    __shared__ unsigned short t[160][34];
    const int tid = threadIdx.x;
    for (int i = tid; i < 160 * 16; i += 256) {
        int l = i >> 4, dp = i & 15;
        unsigned v = *(const unsigned*)(vtok + ((size_t)l * W + col) * 256 + h * 32 + dp * 2);
        *(unsigned*)&t[l][dp * 2] = v;
    }
    __syncthreads();
    unsigned short* dst = vt + (((size_t)h * W + col) * 32) * 160;
    for (int i = tid; i < 32 * 160; i += 256) {
        int d = i / 160, l = i - d * 160;
        dst[i] = t[l][d];
    }
}

// ---------------------------------------------------------------------------
// MFMA attention (verified round 4), output now bf16
__global__ __launch_bounds__(64) void attn_mfma(const unsigned short* __restrict__ qk,
                                                const unsigned short* __restrict__ vt,
                                                unsigned short* __restrict__ o, int W) {
    const int col = blockIdx.x;
    const int h = blockIdx.y;
    const int lane = threadIdx.x;
    const int lr = lane & 15, lq = lane >> 4;
    __shared__ __align__(16) unsigned short P_lds[16][168];

    bf16x8 kf[10];
    #pragma unroll
    for (int m = 0; m < 10; m++) {
        size_t t = (size_t)(m * 16 + lr) * W + col;
        kf[m] = *(const bf16x8*)(qk + t * 512 + 256 + h * 32 + lq * 8);
    }
    const unsigned short* vbase = vt + (((size_t)h * W + col) * 32) * 160;
    bf16x8 vf[2][5];
    #pragma unroll
    for (int md = 0; md < 2; md++)
        #pragma unroll
        for (int c = 0; c < 5; c++)
            vf[md][c] = *(const bf16x8*)(vbase + (size_t)(md * 16 + lr) * 160 + c * 32 + lq * 8);

    const float scale = 0.17677669529663687f;
    for (int n = 0; n < 10; n++) {
        const int q = n * 16 + lr;
        bf16x8 qf = *(const bf16x8*)(qk + ((size_t)q * W + col) * 512 + h * 32 + lq * 8);
        f32x4 p[10];
        #pragma unroll
        for (int m = 0; m < 10; m++)
            p[m] = __builtin_amdgcn_mfma_f32_16x16x32_bf16(kf[m], qf, (f32x4){0.f,0.f,0.f,0.f}, 0, 0, 0);
        const int b = lq * 4 - ((n & 1) * 16 + lr);
        float mx = -1e30f;
        #pragma unroll
        for (int m = 0; m < 10; m++) {
            #pragma unroll
            for (int r = 0; r < 4; r++) {
                int dd = b + (m & 1) * 16 + r;
                float s = ((unsigned)(dd + 5) <= 10u) ? p[m][r] : -1e30f;
                p[m][r] = s;
                mx = fmaxf(mx, s);
            }
        }
        mx = fmaxf(mx, __shfl_xor(mx, 16));
        mx = fmaxf(mx, __shfl_xor(mx, 32));
        float sum = 0.f;
        #pragma unroll
        for (int m = 0; m < 10; m++) {
            #pragma unroll
            for (int r = 0; r < 4; r++) {
                float e = __expf((p[m][r] - mx) * scale);
                p[m][r] = e;
                sum += e;
            }
        }
        sum += __shfl_xor(sum, 16);
        sum += __shfl_xor(sum, 32);
        #pragma unroll
        for (int m = 0; m < 10; m++) {
            ushort4 pk;
            pk.x = f2bf(p[m][0]); pk.y = f2bf(p[m][1]);
            pk.z = f2bf(p[m][2]); pk.w = f2bf(p[m][3]);
            *(ushort4*)&P_lds[lr][m * 16 + lq * 4] = pk;
        }
        f32x4 oa0 = (f32x4){0.f,0.f,0.f,0.f}, oa1 = (f32x4){0.f,0.f,0.f,0.f};
        #pragma unroll
        for (int c = 0; c < 5; c++) {
            bf16x8 pf = *(const bf16x8*)&P_lds[lr][c * 32 + lq * 8];
            oa0 = __builtin_amdgcn_mfma_f32_16x16x32_bf16(vf[0][c], pf, oa0, 0, 0, 0);
            oa1 = __builtin_amdgcn_mfma_f32_16x16x32_bf16(vf[1][c], pf, oa1, 0, 0, 0);
        }
        const float inv = 1.0f / sum;
        unsigned short* op = o + ((size_t)q * W + col) * 256 + h * 32;
        ushort4 s0, s1;
        s0.x = f2bf(oa0[0] * inv); s0.y = f2bf(oa0[1] * inv);
        s0.z = f2bf(oa0[2] * inv); s0.w = f2bf(oa0[3] * inv);
        s1.x = f2bf(oa1[0] * inv); s1.y = f2bf(oa1[1] * inv);
        s1.z = f2bf(oa1[2] * inv); s1.w = f2bf(oa1[3] * inv);
        *(ushort4*)(op + lq * 4)      = s0;
        *(ushort4*)(op + 16 + lq * 4) = s1;
    }
}

// ---------------------------------------------------------------------------
// conv as implicit MFMA GEMM (verified round 3)
__global__ __launch_bounds__(256) void conv_mfma(const unsigned short* __restrict__ xp,
                                                 const unsigned short* __restrict__ wb,
                                                 const float* __restrict__ res,
                                                 float* __restrict__ out, int bb0) {
    const int ptile = blockIdx.x;
    const int slice = blockIdx.y;
    const int lb = slice / 25, n = slice % 25;
    const int bb = bb0 + lb;
    const int y0 = ptile * 4;
    __shared__ unsigned short As[128 * 64];
    __shared__ unsigned short Bs[128 * 64];
    const int tid = threadIdx.x;
    const int lane = tid & 63, w = tid >> 6;
    const int wm = (w >> 1) * 64;
    const int wn = (w & 1) * 64;
    const int lr = lane & 15, lq = lane >> 4;
    const unsigned short* xs = xp + (size_t)slice * 1024 * 128;
    f32x4 acc[4][4];
    #pragma unroll
    for (int m = 0; m < 4; m++)
        #pragma unroll
        for (int nn = 0; nn < 4; nn++)
            acc[m][nn] = (f32x4){0.f, 0.f, 0.f, 0.f};

    for (int tap = 0; tap < 9; tap++) {
        const int dy = tap / 3 - 1, dx = tap % 3 - 1;
        for (int c0 = 0; c0 < 128; c0 += 64) {
            #pragma unroll
            for (int i = 0; i < 4; i++) {
                int id = tid + 256 * i;
                int row = id >> 3, cg = id & 7;
                int py = y0 + (row >> 5) + dy;
                int px = (row & 31) + dx;
                uint4 v = {0u, 0u, 0u, 0u};
                if ((unsigned)py < 32u && (unsigned)px < 32u)
                    v = *(const uint4*)(xs + ((size_t)(py * 32 + px) * 128 + c0 + cg * 8));
                int boff = row * 128 + ((cg * 16) ^ ((row & 7) << 4));
                *(uint4*)((char*)As + boff) = v;
            }
            #pragma unroll
            for (int i = 0; i < 4; i++) {
                int id = tid + 256 * i;
                int row = id >> 3, cg = id & 7;
                uint4 v = *(const uint4*)(wb + (((size_t)tap * 128 + row) * 128 + c0 + cg * 8));
                int boff = row * 128 + ((cg * 16) ^ ((row & 7) << 4));
                *(uint4*)((char*)Bs + boff) = v;
            }
            __syncthreads();
            #pragma unroll
            for (int ks = 0; ks < 2; ks++) {
                bf16x8 wf[4], xf[4];
                #pragma unroll
                for (int m = 0; m < 4; m++) {
                    int row = wm + m * 16 + lr;
                    int boff = row * 128 + ((ks * 64 + lq * 16) ^ ((row & 7) << 4));
                    wf[m] = *(const bf16x8*)((const char*)Bs + boff);
                }
                #pragma unroll
                for (int nn = 0; nn < 4; nn++) {
                    int row = wn + nn * 16 + lr;
                    int boff = row * 128 + ((ks * 64 + lq * 16) ^ ((row & 7) << 4));
                    xf[nn] = *(const bf16x8*)((const char*)As + boff);
                }
                #pragma unroll
                for (int m = 0; m < 4; m++)
                    #pragma unroll
                    for (int nn = 0; nn < 4; nn++)
                        acc[m][nn] = __builtin_amdgcn_mfma_f32_16x16x32_bf16(wf[m], xf[nn], acc[m][nn], 0, 0, 0);
            }
            __syncthreads();
        }
    }
    #pragma unroll
    for (int m = 0; m < 4; m++) {
        int co0 = wm + m * 16 + lq * 4;
        #pragma unroll
        for (int r = 0; r < 4; r++) {
            size_t rowoff = (((size_t)(bb * 128 + co0 + r) * 25 + n) * 1024) + ptile * 128;
            #pragma unroll
            for (int nn = 0; nn < 4; nn++) {
                int pix = wn + nn * 16 + lr;
                out[rowoff + pix] = acc[m][nn][r] + res[rowoff + pix];
            }
        }
    }
}

// ---------------------------------------------------------------------------
extern "C" void kernel_launch(void* const* d_in, const int* in_sizes, int n_in,
                              void* d_out, int out_size, void* d_ws, size_t ws_size,
                              hipStream_t stream) {
    (void)in_sizes; (void)n_in; (void)out_size;
    const float* buffer     = (const float*)d_in[0];
    const float* Win        = (const float*)d_in[1];
    const float* ln_w       = (const float*)d_in[2];
    const float* ln_b       = (const float*)d_in[3];
    const float* in_proj    = (const float*)d_in[4];
    const float* attn_out_w = (const float*)d_in[5];
    const float* ffn_ln_w   = (const float*)d_in[6];
    const float* ffn_ln_b   = (const float*)d_in[7];
    const float* ff1        = (const float*)d_in[8];
    const float* ff2        = (const float*)d_in[9];
    const float* Wout       = (const float*)d_in[10];
    const float* conv_w     = (const float*)d_in[11];
    float* out = (float*)d_out;
    float* ws  = (float*)d_ws;

    int NBB = (ws_size >= (size_t)2 * 25600 * 1408 * 4) ? 2 : 1;
    const int W = NBB * 160;
    const size_t T = (size_t)NBB * 25600;

    // layout (float-slot offsets); all bf16 buffers alias float regions
    unsigned short* x0b   = (unsigned short*)ws;                 // T*128 bf16
    float*          A     = ws + T * 128;                        // T*256 f32 residual
    unsigned short* tnb   = (unsigned short*)(ws + T * 384);     // T*256 bf16
    unsigned short* Abf   = (unsigned short*)(ws + T * 512);     // T*256 bf16
    float*          C     = ws + T * 640;                        // T*512 region
    unsigned short* QKtok = (unsigned short*)C;                  // T*512 bf16
    unsigned short* Vtok  = (unsigned short*)(C + T * 256);      // T*256 bf16
    unsigned short* Vt    = (unsigned short*)(C + T * 384);      // T*256 bf16
    unsigned short* hidb  = (unsigned short*)C;                  // T*512 bf16 (QK dead)
    unsigned short* xp    = (unsigned short*)C;                  // T*128 bf16 (hid dead)
    unsigned short* Db    = (unsigned short*)(ws + T * 1152);    // T*256 bf16
    unsigned short* wg    = (unsigned short*)(ws + T * 1280);    // 589824 bf16
    unsigned short* wb    = (unsigned short*)(ws + T * 1280 + 294912); // 147456 bf16

    const unsigned short* Winb  = wg;
    const unsigned short* Wqkb  = wg + 32768;            // first 512 rows of in_proj
    const unsigned short* Wvb   = wg + 32768 + 512 * 256;
    const unsigned short* Waob  = wg + 229376;
    const unsigned short* Wff1b = wg + 294912;
    const unsigned short* Wff2b = wg + 425984;
    const unsigned short* Woutb = wg + 557056;

    const int GM = (int)(T / 128);

    conv_weights<<<2304, 256, 0, stream>>>(Win, in_proj, attn_out_w, ff1, ff2, Wout, wg);
    repack_w<<<576, 256, 0, stream>>>(conv_w, wb);

    for (int pass = 0; pass < 2; pass++) {
        const float* src = (pass == 0) ? buffer : out;
        for (int bb0 = 0; bb0 < 2; bb0 += NBB) {
            if (pass == 0) gather1<<<dim3(128, 25, NBB), 256, 0, stream>>>(src, x0b, W, bb0);
            else           gather2<<<dim3(128, 25, NBB), 256, 0, stream>>>(src, x0b, W, bb0);

            // tok = x0 @ Win^T (K=128): A f32 + Abf bf16
            gemm_bf16<<<dim3(GM, 2), 256, 0, stream>>>(x0b, Winb, A, Abf, nullptr, 256, 128, 0);
            ln_kernel<<<(int)(T / 4), 256, 0, stream>>>(A, tnb, ln_w, ln_b);
            // qk = tn @ [Wq;Wk]^T (N=512) -> bf16
            gemm_bf16<<<dim3(GM, 4), 256, 0, stream>>>(tnb, Wqkb, nullptr, QKtok, nullptr, 512, 256, 0);
            // vv = tok @ Wv^T -> bf16
            gemm_bf16<<<dim3(GM, 2), 256, 0, stream>>>(Abf, Wvb, nullptr, Vtok, nullptr, 256, 256, 0);
            vtrans<<<dim3(W, 8), 256, 0, stream>>>(Vtok, Vt, W);
            attn_mfma<<<dim3(W, 8), 64, 0, stream>>>(QKtok, Vt, Db, W);
            // tok += ob @ attn_out_w^T  (f32 out only)
            gemm_bf16<<<dim3(GM, 2), 256, 0, stream>>>(Db, Waob, A, nullptr, A, 256, 256, 0);
            ln_kernel<<<(int)(T / 4), 256, 0, stream>>>(A, tnb, ffn_ln_w, ffn_ln_b);
            // hidden = relu(tn2 @ ff1^T) (N=512) -> bf16
            gemm_bf16<<<dim3(GM, 4), 256, 0, stream>>>(tnb, Wff1b, nullptr, hidb, nullptr, 512, 256, 1);
            // final tok = hidden @ ff2^T + tok (K=512) -> bf16 only (Wout input)
            gemm_bf16<<<dim3(GM, 2), 256, 0, stream>>>(hidb, Wff2b, nullptr, Abf, A, 256, 512, 0);
            // ot = tok @ Wout^T (N=128) -> bf16 straight into scatter input
            gemm_bf16<<<dim3(GM, 1), 256, 0, stream>>>(Abf, Woutb, nullptr, x0b, nullptr, 128, 256, 0);

            if (pass == 0) scatterP1<<<dim3(32, 25, NBB), 256, 0, stream>>>(x0b, xp, W);
            else           scatterP2<<<dim3(32, 25, NBB), 256, 0, stream>>>(x0b, xp, W);

            conv_mfma<<<dim3(8, NBB * 25), 256, 0, stream>>>(
                xp, wb, (pass == 0) ? buffer : (const float*)out, out, bb0);
        }
    }
}

// Round 7
// 816.063 us; speedup vs baseline: 5.2820x; 1.7344x over previous
//
#include <hip/hip_runtime.h>
#include <math.h>
#include <stdint.h>

typedef __attribute__((ext_vector_type(8))) short bf16x8;
typedef __attribute__((ext_vector_type(4))) float f32x4;

static __device__ __forceinline__ unsigned short f2bf(float f) {
    unsigned u = __builtin_bit_cast(unsigned, f);
    unsigned r = u + 0x7fffu + ((u >> 16) & 1u);   // RNE
    return (unsigned short)(r >> 16);
}
static __device__ __forceinline__ float bf2f(unsigned short h) {
    return __builtin_bit_cast(float, ((unsigned)h) << 16);
}
// async global->LDS, 16B per lane; lds dest = uniform base + lane*16
static __device__ __forceinline__ void gload_lds16(const void* g, void* l) {
    __builtin_amdgcn_global_load_lds((const __attribute__((address_space(1))) unsigned int*)g,
                                     (__attribute__((address_space(3))) unsigned int*)l, 16, 0, 0);
}

// ---------------------------------------------------------------------------
// gather pass1: x0b[t'][cc] (bf16) = src[bb][cc][u*5+v][y][x]
__global__ __launch_bounds__(256) void gather1(const float* __restrict__ src,
                                               unsigned short* __restrict__ x0, int W, int bb0) {
    int cct = blockIdx.x & 3, y = blockIdx.x >> 2;
    int n = blockIdx.y; int u = n / 5, v = n % 5;
    int lb = blockIdx.z, bb = bb0 + lb;
    __shared__ float tile[32][33];
    int tx = threadIdx.x & 31, tg = threadIdx.x >> 5;
    const float* s = src + (((size_t)(bb * 128 + cct * 32) * 25 + n) * 32 + y) * 32;
    #pragma unroll
    for (int i = 0; i < 4; i++) {
        int cl = tg + 8 * i;
        tile[cl][tx] = s[(size_t)cl * 25600 + tx];
    }
    __syncthreads();
    unsigned short* d = x0 + ((size_t)(u * 32 + y) * W + lb * 160 + v * 32) * 128 + cct * 32;
    #pragma unroll
    for (int i = 0; i < 4; i++) {
        int xx = tg + 8 * i;
        d[(size_t)xx * 128 + tx] = f2bf(tile[tx][xx]);
    }
}

// gather pass2
__global__ __launch_bounds__(256) void gather2(const float* __restrict__ src,
                                               unsigned short* __restrict__ x0, int W, int bb0) {
    int cct = blockIdx.x & 3, x = blockIdx.x >> 2;
    int n = blockIdx.y; int u = n / 5, v = n % 5;
    int lb = blockIdx.z, bb = bb0 + lb;
    __shared__ float tile[32][33];
    int tx = threadIdx.x & 31, tg = threadIdx.x >> 5;
    const float* s = src + (((size_t)(bb * 128 + cct * 32) * 25 + n) * 32) * 32 + x;
    #pragma unroll
    for (int i = 0; i < 4; i++) {
        int cl = tg + 8 * i;
        tile[cl][tx] = s[(size_t)cl * 25600 + tx * 32];
    }
    __syncthreads();
    unsigned short* d = x0 + ((size_t)(v * 32 + x) * W + lb * 160 + u * 32) * 128 + cct * 32;
    #pragma unroll
    for (int i = 0; i < 4; i++) {
        int yy = tg + 8 * i;
        d[(size_t)yy * 128 + tx] = f2bf(tile[tx][yy]);
    }
}

// ---------------------------------------------------------------------------
// conv weight repack: conv_w[co][ci][tap(9)] f32 -> wb[tap][co][ci] bf16
__global__ __launch_bounds__(256) void repack_w(const float* __restrict__ cw,
                                                unsigned short* __restrict__ wb) {
    int g = blockIdx.x * 256 + threadIdx.x;
    int co = g / 1152;
    int rem = g - co * 1152;
    int ci = rem / 9, tap = rem - ci * 9;
    wb[((size_t)tap * 128 + co) * 128 + ci] = f2bf(cw[g]);
}

// GEMM weights -> one bf16 buffer (layout preserved [N][K])
__global__ __launch_bounds__(256) void conv_weights(const float* __restrict__ Win,
                                                    const float* __restrict__ in_proj,
                                                    const float* __restrict__ attn_out_w,
                                                    const float* __restrict__ ff1,
                                                    const float* __restrict__ ff2,
                                                    const float* __restrict__ Wout,
                                                    unsigned short* __restrict__ wg) {
    int g = blockIdx.x * 256 + threadIdx.x;      // 589824 total
    float v;
    if      (g < 32768)  v = Win[g];
    else if (g < 229376) v = in_proj[g - 32768];
    else if (g < 294912) v = attn_out_w[g - 229376];
    else if (g < 425984) v = ff1[g - 294912];
    else if (g < 557056) v = ff2[g - 425984];
    else                 v = Wout[g - 557056];
    wg[g] = f2bf(v);
}

// ---------------------------------------------------------------------------
// LayerNorm over E=256, bf16 in -> bf16 out (f32 stats)
__global__ __launch_bounds__(256) void ln_bf16(const unsigned short* __restrict__ in,
                                               unsigned short* __restrict__ out,
                                               const float* __restrict__ w, const float* __restrict__ b) {
    int tok = blockIdx.x * 4 + (threadIdx.x >> 6);
    int lane = threadIdx.x & 63;
    ushort4 h4 = ((const ushort4*)(in + (size_t)tok * 256))[lane];
    float vx = bf2f(h4.x), vy = bf2f(h4.y), vz = bf2f(h4.z), vw = bf2f(h4.w);
    float s = vx + vy + vz + vw;
    #pragma unroll
    for (int off = 32; off > 0; off >>= 1) s += __shfl_xor(s, off);
    float mu = s * (1.0f / 256.0f);
    float dx = vx - mu, dy = vy - mu, dz = vz - mu, dw = vw - mu;
    float vs = dx * dx + dy * dy + dz * dz + dw * dw;
    #pragma unroll
    for (int off = 32; off > 0; off >>= 1) vs += __shfl_xor(vs, off);
    float inv = rsqrtf(vs * (1.0f / 256.0f) + 1e-5f);
    float4 wv = ((const float4*)w)[lane];
    float4 bv = ((const float4*)b)[lane];
    ushort4 o4;
    o4.x = f2bf(dx * inv * wv.x + bv.x);
    o4.y = f2bf(dy * inv * wv.y + bv.y);
    o4.z = f2bf(dz * inv * wv.z + bv.z);
    o4.w = f2bf(dw * inv * wv.w + bv.w);
    *(ushort4*)(out + (size_t)tok * 256 + lane * 4) = o4;
}

// ---------------------------------------------------------------------------
// bf16 MFMA GEMM, 2-phase double-buffered global_load_lds pipeline.
// Y = X[M,K] @ Wt[N,K]^T (+Rb bf16) (relu?) -> Yb bf16.
// spass=1/2: fused scatter epilogue (row -> [slice][pix][ci] layout).
// LDS: linear dest + inverse-swizzled global source; reads use XOR swizzle.
__global__ __launch_bounds__(256) void gemm_bf16(const unsigned short* __restrict__ X,
                                                 const unsigned short* __restrict__ Wt,
                                                 unsigned short* __restrict__ Yb,
                                                 const unsigned short* __restrict__ Rb,
                                                 int N, int K, int relu, int spass, int W) {
    __shared__ unsigned short As[2][128 * 64];
    __shared__ unsigned short Bs[2][128 * 64];
    const int bm = blockIdx.x * 128, bn = blockIdx.y * 128;
    const int tid = threadIdx.x;
    const int lane = tid & 63, w = tid >> 6;
    const int wm = (w >> 1) * 64, wn = (w & 1) * 64;
    const int lr = lane & 15, lq = lane >> 4;
    f32x4 acc[4][4];
    #pragma unroll
    for (int m = 0; m < 4; m++)
        #pragma unroll
        for (int n = 0; n < 4; n++)
            acc[m][n] = (f32x4){0.f, 0.f, 0.f, 0.f};

    // stage one K-tile (BK=64) into buffer bsel: per wave 4 chunks x 1024B each
    // chunk = 8 rows; lane covers (row = base + lane>>3, slot = lane&7);
    // global col-group = slot ^ (row&7)  (inverse of read-side XOR swizzle)
    const int srow = lane >> 3, sslot = lane & 7;
    auto STAGE = [&](int bsel, int k0) {
        #pragma unroll
        for (int c = 0; c < 4; ++c) {
            int row = (w << 5) + (c << 3) + srow;
            int cg = sslot ^ (row & 7);
            gload_lds16(X  + (size_t)(bm + row) * K + k0 + cg * 8,
                        &As[bsel][(w << 11) + (c << 9)]);
            gload_lds16(Wt + (size_t)(bn + row) * K + k0 + cg * 8,
                        &Bs[bsel][(w << 11) + (c << 9)]);
        }
    };

    const int nt = K >> 6;
    STAGE(0, 0);
    __syncthreads();                      // drains vmcnt(0) per barrier semantics
    int cur = 0;
    for (int t = 0; t < nt; ++t) {
        if (t + 1 < nt) STAGE(cur ^ 1, (t + 1) << 6);
        const char* Ab = (const char*)As[cur];
        const char* Bb = (const char*)Bs[cur];
        #pragma unroll
        for (int ks = 0; ks < 2; ks++) {
            bf16x8 af[4], bf[4];
            #pragma unroll
            for (int m = 0; m < 4; m++) {
                int row = wm + m * 16 + lr;
                int boff = row * 128 + ((ks * 64 + lq * 16) ^ ((row & 7) << 4));
                af[m] = *(const bf16x8*)(Ab + boff);
            }
            #pragma unroll
            for (int n = 0; n < 4; n++) {
                int row = wn + n * 16 + lr;
                int boff = row * 128 + ((ks * 64 + lq * 16) ^ ((row & 7) << 4));
                bf[n] = *(const bf16x8*)(Bb + boff);
            }
            #pragma unroll
            for (int m = 0; m < 4; m++)
                #pragma unroll
                for (int n = 0; n < 4; n++)
                    acc[m][n] = __builtin_amdgcn_mfma_f32_16x16x32_bf16(af[m], bf[n], acc[m][n], 0, 0, 0);
        }
        if (t + 1 < nt) __syncthreads();  // waits stage(t+1) loads + read-done
        cur ^= 1;
    }

    #pragma unroll
    for (int m = 0; m < 4; m++) {
        #pragma unroll
        for (int r = 0; r < 4; r++) {
            int row = bm + wm + m * 16 + lq * 4 + r;
            size_t base;
            if (spass == 0) {
                base = (size_t)row * N;
            } else {
                int l = row / W, c = row - l * W;
                int lb = (c >= 160) ? 1 : 0, sp = c - lb * 160;
                int sl_, pix;
                if (spass == 1) { int u = l >> 5, y = l & 31, v = sp >> 5, x = sp & 31;
                                  sl_ = lb * 25 + u * 5 + v; pix = y * 32 + x; }
                else            { int v = l >> 5, x = l & 31, u = sp >> 5, y = sp & 31;
                                  sl_ = lb * 25 + u * 5 + v; pix = y * 32 + x; }
                base = ((size_t)sl_ * 1024 + pix) * 128;
            }
            #pragma unroll
            for (int n = 0; n < 4; n++) {
                int col = bn + wn + n * 16 + lr;
                float val = acc[m][n][r];
                if (Rb) val += bf2f(Rb[(size_t)row * N + col]);
                if (relu) val = fmaxf(val, 0.0f);
                Yb[base + col] = f2bf(val);
            }
        }
    }
}

// ---------------------------------------------------------------------------
// V transpose: Vtok[t][256] bf16 -> Vt[h][col][d(32)][l(160)] bf16
__global__ __launch_bounds__(256) void vtrans(const unsigned short* __restrict__ vtok,
                                              unsigned short* __restrict__ vt, int W) {
    const int col = blockIdx.x, h = blockIdx.y;
    __shared__ unsigned short t[160][34];
    const int tid = threadIdx.x;
    for (int i = tid; i < 160 * 16; i += 256) {
        int l = i >> 4, dp = i & 15;
        unsigned v = *(const unsigned*)(vtok + ((size_t)l * W + col) * 256 + h * 32 + dp * 2);
        *(unsigned*)&t[l][dp * 2] = v;
    }
    __syncthreads();
    unsigned short* dst = vt + (((size_t)h * W + col) * 32) * 160;
    for (int i = tid; i < 32 * 160; i += 256) {
        int d = i / 160, l = i - d * 160;
        dst[i] = t[l][d];
    }
}

// ---------------------------------------------------------------------------
// MFMA attention (verified round 4/5), bf16 in/out
__global__ __launch_bounds__(64) void attn_mfma(const unsigned short* __restrict__ qk,
                                                const unsigned short* __restrict__ vt,
                                                unsigned short* __restrict__ o, int W) {
    const int col = blockIdx.x;
    const int h = blockIdx.y;
    const int lane = threadIdx.x;
    const int lr = lane & 15, lq = lane >> 4;
    __shared__ __align__(16) unsigned short P_lds[16][168];

    bf16x8 kf[10];
    #pragma unroll
    for (int m = 0; m < 10; m++) {
        size_t t = (size_t)(m * 16 + lr) * W + col;
        kf[m] = *(const bf16x8*)(qk + t * 512 + 256 + h * 32 + lq * 8);
    }
    const unsigned short* vbase = vt + (((size_t)h * W + col) * 32) * 160;
    bf16x8 vf[2][5];
    #pragma unroll
    for (int md = 0; md < 2; md++)
        #pragma unroll
        for (int c = 0; c < 5; c++)
            vf[md][c] = *(const bf16x8*)(vbase + (size_t)(md * 16 + lr) * 160 + c * 32 + lq * 8);

    const float scale = 0.17677669529663687f;
    for (int n = 0; n < 10; n++) {
        const int q = n * 16 + lr;
        bf16x8 qf = *(const bf16x8*)(qk + ((size_t)q * W + col) * 512 + h * 32 + lq * 8);
        f32x4 p[10];
        #pragma unroll
        for (int m = 0; m < 10; m++)
            p[m] = __builtin_amdgcn_mfma_f32_16x16x32_bf16(kf[m], qf, (f32x4){0.f,0.f,0.f,0.f}, 0, 0, 0);
        const int b = lq * 4 - ((n & 1) * 16 + lr);
        float mx = -1e30f;
        #pragma unroll
        for (int m = 0; m < 10; m++) {
            #pragma unroll
            for (int r = 0; r < 4; r++) {
                int dd = b + (m & 1) * 16 + r;
                float s = ((unsigned)(dd + 5) <= 10u) ? p[m][r] : -1e30f;
                p[m][r] = s;
                mx = fmaxf(mx, s);
            }
        }
        mx = fmaxf(mx, __shfl_xor(mx, 16));
        mx = fmaxf(mx, __shfl_xor(mx, 32));
        float sum = 0.f;
        #pragma unroll
        for (int m = 0; m < 10; m++) {
            #pragma unroll
            for (int r = 0; r < 4; r++) {
                float e = __expf((p[m][r] - mx) * scale);
                p[m][r] = e;
                sum += e;
            }
        }
        sum += __shfl_xor(sum, 16);
        sum += __shfl_xor(sum, 32);
        #pragma unroll
        for (int m = 0; m < 10; m++) {
            ushort4 pk;
            pk.x = f2bf(p[m][0]); pk.y = f2bf(p[m][1]);
            pk.z = f2bf(p[m][2]); pk.w = f2bf(p[m][3]);
            *(ushort4*)&P_lds[lr][m * 16 + lq * 4] = pk;
        }
        f32x4 oa0 = (f32x4){0.f,0.f,0.f,0.f}, oa1 = (f32x4){0.f,0.f,0.f,0.f};
        #pragma unroll
        for (int c = 0; c < 5; c++) {
            bf16x8 pf = *(const bf16x8*)&P_lds[lr][c * 32 + lq * 8];
            oa0 = __builtin_amdgcn_mfma_f32_16x16x32_bf16(vf[0][c], pf, oa0, 0, 0, 0);
            oa1 = __builtin_amdgcn_mfma_f32_16x16x32_bf16(vf[1][c], pf, oa1, 0, 0, 0);
        }
        const float inv = 1.0f / sum;
        unsigned short* op = o + ((size_t)q * W + col) * 256 + h * 32;
        ushort4 s0, s1;
        s0.x = f2bf(oa0[0] * inv); s0.y = f2bf(oa0[1] * inv);
        s0.z = f2bf(oa0[2] * inv); s0.w = f2bf(oa0[3] * inv);
        s1.x = f2bf(oa1[0] * inv); s1.y = f2bf(oa1[1] * inv);
        s1.z = f2bf(oa1[2] * inv); s1.w = f2bf(oa1[3] * inv);
        *(ushort4*)(op + lq * 4)      = s0;
        *(ushort4*)(op + 16 + lq * 4) = s1;
    }
}

// ---------------------------------------------------------------------------
// conv as implicit MFMA GEMM (verified round 3)
__global__ __launch_bounds__(256) void conv_mfma(const unsigned short* __restrict__ xp,
                                                 const unsigned short* __restrict__ wb,
                                                 const float* __restrict__ res,
                                                 float* __restrict__ out, int bb0) {
    const int ptile = blockIdx.x;
    const int slice = blockIdx.y;
    const int lb = slice / 25, n = slice % 25;
    const int bb = bb0 + lb;
    const int y0 = ptile * 4;
    __shared__ unsigned short As[128 * 64];
    __shared__ unsigned short Bs[128 * 64];
    const int tid = threadIdx.x;
    const int lane = tid & 63, w = tid >> 6;
    const int wm = (w >> 1) * 64;
    const int wn = (w & 1) * 64;
    const int lr = lane & 15, lq = lane >> 4;
    const unsigned short* xs = xp + (size_t)slice * 1024 * 128;
    f32x4 acc[4][4];
    #pragma unroll
    for (int m = 0; m < 4; m++)
        #pragma unroll
        for (int nn = 0; nn < 4; nn++)
            acc[m][nn] = (f32x4){0.f, 0.f, 0.f, 0.f};

    for (int tap = 0; tap < 9; tap++) {
        const int dy = tap / 3 - 1, dx = tap % 3 - 1;
        for (int c0 = 0; c0 < 128; c0 += 64) {
            #pragma unroll
            for (int i = 0; i < 4; i++) {
                int id = tid + 256 * i;
                int row = id >> 3, cg = id & 7;
                int py = y0 + (row >> 5) + dy;
                int px = (row & 31) + dx;
                uint4 v = {0u, 0u, 0u, 0u};
                if ((unsigned)py < 32u && (unsigned)px < 32u)
                    v = *(const uint4*)(xs + ((size_t)(py * 32 + px) * 128 + c0 + cg * 8));
                int boff = row * 128 + ((cg * 16) ^ ((row & 7) << 4));
                *(uint4*)((char*)As + boff) = v;
            }
            #pragma unroll
            for (int i = 0; i < 4; i++) {
                int id = tid + 256 * i;
                int row = id >> 3, cg = id & 7;
                uint4 v = *(const uint4*)(wb + (((size_t)tap * 128 + row) * 128 + c0 + cg * 8));
                int boff = row * 128 + ((cg * 16) ^ ((row & 7) << 4));
                *(uint4*)((char*)Bs + boff) = v;
            }
            __syncthreads();
            #pragma unroll
            for (int ks = 0; ks < 2; ks++) {
                bf16x8 wf[4], xf[4];
                #pragma unroll
                for (int m = 0; m < 4; m++) {
                    int row = wm + m * 16 + lr;
                    int boff = row * 128 + ((ks * 64 + lq * 16) ^ ((row & 7) << 4));
                    wf[m] = *(const bf16x8*)((const char*)Bs + boff);
                }
                #pragma unroll
                for (int nn = 0; nn < 4; nn++) {
                    int row = wn + nn * 16 + lr;
                    int boff = row * 128 + ((ks * 64 + lq * 16) ^ ((row & 7) << 4));
                    xf[nn] = *(const bf16x8*)((const char*)As + boff);
                }
                #pragma unroll
                for (int m = 0; m < 4; m++)
                    #pragma unroll
                    for (int nn = 0; nn < 4; nn++)
                        acc[m][nn] = __builtin_amdgcn_mfma_f32_16x16x32_bf16(wf[m], xf[nn], acc[m][nn], 0, 0, 0);
            }
            __syncthreads();
        }
    }
    #pragma unroll
    for (int m = 0; m < 4; m++) {
        int co0 = wm + m * 16 + lq * 4;
        #pragma unroll
        for (int r = 0; r < 4; r++) {
            size_t rowoff = (((size_t)(bb * 128 + co0 + r) * 25 + n) * 1024) + ptile * 128;
            #pragma unroll
            for (int nn = 0; nn < 4; nn++) {
                int pix = wn + nn * 16 + lr;
                out[rowoff + pix] = acc[m][nn][r] + res[rowoff + pix];
            }
        }
    }
}

// ---------------------------------------------------------------------------
extern "C" void kernel_launch(void* const* d_in, const int* in_sizes, int n_in,
                              void* d_out, int out_size, void* d_ws, size_t ws_size,
                              hipStream_t stream) {
    (void)in_sizes; (void)n_in; (void)out_size;
    const float* buffer     = (const float*)d_in[0];
    const float* Win        = (const float*)d_in[1];
    const float* ln_w       = (const float*)d_in[2];
    const float* ln_b       = (const float*)d_in[3];
    const float* in_proj    = (const float*)d_in[4];
    const float* attn_out_w = (const float*)d_in[5];
    const float* ffn_ln_w   = (const float*)d_in[6];
    const float* ffn_ln_b   = (const float*)d_in[7];
    const float* ff1        = (const float*)d_in[8];
    const float* ff2        = (const float*)d_in[9];
    const float* Wout       = (const float*)d_in[10];
    const float* conv_w     = (const float*)d_in[11];
    float* out = (float*)d_out;
    float* ws  = (float*)d_ws;

    int NBB = (ws_size >= (size_t)2 * 25600 * 1408 * 4) ? 2 : 1;
    const int W = NBB * 160;
    const size_t T = (size_t)NBB * 25600;

    // layout (float-slot offsets); all bf16
    unsigned short* x0b   = (unsigned short*)ws;                 // T*128 bf16
    unsigned short* Abf   = (unsigned short*)(ws + T * 64);      // T*256 bf16 residual
    unsigned short* tnb   = (unsigned short*)(ws + T * 192);     // T*256 bf16
    float*          C     = ws + T * 320;                        // T*512 fl region
    unsigned short* QKtok = (unsigned short*)C;                  // T*512 bf16
    unsigned short* Vtok  = (unsigned short*)(C + T * 256);      // T*256 bf16
    unsigned short* Vt    = (unsigned short*)(C + T * 384);      // T*256 bf16
    unsigned short* hidb  = (unsigned short*)C;                  // T*512 bf16 (QK dead)
    unsigned short* xp    = (unsigned short*)C;                  // T*128 bf16 (hid dead)
    unsigned short* Db    = (unsigned short*)(ws + T * 832);     // T*256 bf16
    unsigned short* wg    = (unsigned short*)(ws + T * 960);     // 589824 bf16
    unsigned short* wb    = (unsigned short*)(ws + T * 960 + 294912); // 147456 bf16

    const unsigned short* Winb  = wg;
    const unsigned short* Wqkb  = wg + 32768;
    const unsigned short* Wvb   = wg + 32768 + 512 * 256;
    const unsigned short* Waob  = wg + 229376;
    const unsigned short* Wff1b = wg + 294912;
    const unsigned short* Wff2b = wg + 425984;
    const unsigned short* Woutb = wg + 557056;

    const int GM = (int)(T / 128);

    conv_weights<<<2304, 256, 0, stream>>>(Win, in_proj, attn_out_w, ff1, ff2, Wout, wg);
    repack_w<<<576, 256, 0, stream>>>(conv_w, wb);

    for (int pass = 0; pass < 2; pass++) {
        const float* src = (pass == 0) ? buffer : out;
        for (int bb0 = 0; bb0 < 2; bb0 += NBB) {
            if (pass == 0) gather1<<<dim3(128, 25, NBB), 256, 0, stream>>>(src, x0b, W, bb0);
            else           gather2<<<dim3(128, 25, NBB), 256, 0, stream>>>(src, x0b, W, bb0);

            // tok = x0 @ Win^T (K=128) -> Abf
            gemm_bf16<<<dim3(GM, 2), 256, 0, stream>>>(x0b, Winb, Abf, nullptr, 256, 128, 0, 0, W);
            ln_bf16<<<(int)(T / 4), 256, 0, stream>>>(Abf, tnb, ln_w, ln_b);
            // qk = tn @ [Wq;Wk]^T (N=512)
            gemm_bf16<<<dim3(GM, 4), 256, 0, stream>>>(tnb, Wqkb, QKtok, nullptr, 512, 256, 0, 0, W);
            // vv = tok @ Wv^T
            gemm_bf16<<<dim3(GM, 2), 256, 0, stream>>>(Abf, Wvb, Vtok, nullptr, 256, 256, 0, 0, W);
            vtrans<<<dim3(W, 8), 256, 0, stream>>>(Vtok, Vt, W);
            attn_mfma<<<dim3(W, 8), 64, 0, stream>>>(QKtok, Vt, Db, W);
            // tok += ob @ attn_out_w^T  (in-place bf16 residual)
            gemm_bf16<<<dim3(GM, 2), 256, 0, stream>>>(Db, Waob, Abf, Abf, 256, 256, 0, 0, W);
            ln_bf16<<<(int)(T / 4), 256, 0, stream>>>(Abf, tnb, ffn_ln_w, ffn_ln_b);
            // hidden = relu(tn2 @ ff1^T) (N=512)
            gemm_bf16<<<dim3(GM, 4), 256, 0, stream>>>(tnb, Wff1b, hidb, nullptr, 512, 256, 1, 0, W);
            // tok += hidden @ ff2^T (K=512, in-place residual)
            gemm_bf16<<<dim3(GM, 2), 256, 0, stream>>>(hidb, Wff2b, Abf, Abf, 256, 512, 0, 0, W);
            // ot = tok @ Wout^T (N=128) -> fused scatter into xp (pixel-major)
            gemm_bf16<<<dim3(GM, 1), 256, 0, stream>>>(Abf, Woutb, xp, nullptr, 128, 256, 0, pass + 1, W);

            conv_mfma<<<dim3(8, NBB * 25), 256, 0, stream>>>(
                xp, wb, (pass == 0) ? buffer : (const float*)out, out, bb0);
        }
    }
}

// Round 8
// 690.152 us; speedup vs baseline: 6.2457x; 1.1824x over previous
//
#include <hip/hip_runtime.h>
#include <math.h>
#include <stdint.h>

typedef __attribute__((ext_vector_type(8))) short bf16x8;
typedef __attribute__((ext_vector_type(4))) float f32x4;

static __device__ __forceinline__ unsigned short f2bf(float f) {
    unsigned u = __builtin_bit_cast(unsigned, f);
    unsigned r = u + 0x7fffu + ((u >> 16) & 1u);   // RNE
    return (unsigned short)(r >> 16);
}
static __device__ __forceinline__ float bf2f(unsigned short h) {
    return __builtin_bit_cast(float, ((unsigned)h) << 16);
}
// async global->LDS, 16B per lane; lds dest = uniform base + lane*16
static __device__ __forceinline__ void gload_lds16(const void* g, void* l) {
    __builtin_amdgcn_global_load_lds((const __attribute__((address_space(1))) unsigned int*)g,
                                     (__attribute__((address_space(3))) unsigned int*)l, 16, 0, 0);
}

// ---------------------------------------------------------------------------
// gather pass1: x0b[t'][cc] (bf16) = src[bb][cc][u*5+v][y][x]
__global__ __launch_bounds__(256) void gather1(const float* __restrict__ src,
                                               unsigned short* __restrict__ x0, int W, int bb0) {
    int cct = blockIdx.x & 3, y = blockIdx.x >> 2;
    int n = blockIdx.y; int u = n / 5, v = n % 5;
    int lb = blockIdx.z, bb = bb0 + lb;
    __shared__ float tile[32][33];
    int tx = threadIdx.x & 31, tg = threadIdx.x >> 5;
    const float* s = src + (((size_t)(bb * 128 + cct * 32) * 25 + n) * 32 + y) * 32;
    #pragma unroll
    for (int i = 0; i < 4; i++) {
        int cl = tg + 8 * i;
        tile[cl][tx] = s[(size_t)cl * 25600 + tx];
    }
    __syncthreads();
    unsigned short* d = x0 + ((size_t)(u * 32 + y) * W + lb * 160 + v * 32) * 128 + cct * 32;
    #pragma unroll
    for (int i = 0; i < 4; i++) {
        int xx = tg + 8 * i;
        d[(size_t)xx * 128 + tx] = f2bf(tile[tx][xx]);
    }
}

// gather pass2
__global__ __launch_bounds__(256) void gather2(const float* __restrict__ src,
                                               unsigned short* __restrict__ x0, int W, int bb0) {
    int cct = blockIdx.x & 3, x = blockIdx.x >> 2;
    int n = blockIdx.y; int u = n / 5, v = n % 5;
    int lb = blockIdx.z, bb = bb0 + lb;
    __shared__ float tile[32][33];
    int tx = threadIdx.x & 31, tg = threadIdx.x >> 5;
    const float* s = src + (((size_t)(bb * 128 + cct * 32) * 25 + n) * 32) * 32 + x;
    #pragma unroll
    for (int i = 0; i < 4; i++) {
        int cl = tg + 8 * i;
        tile[cl][tx] = s[(size_t)cl * 25600 + tx * 32];
    }
    __syncthreads();
    unsigned short* d = x0 + ((size_t)(v * 32 + x) * W + lb * 160 + u * 32) * 128 + cct * 32;
    #pragma unroll
    for (int i = 0; i < 4; i++) {
        int yy = tg + 8 * i;
        d[(size_t)yy * 128 + tx] = f2bf(tile[tx][yy]);
    }
}

// ---------------------------------------------------------------------------
// conv weight repack: conv_w[co][ci][tap(9)] f32 -> wb[tap][co][ci] bf16
__global__ __launch_bounds__(256) void repack_w(const float* __restrict__ cw,
                                                unsigned short* __restrict__ wb) {
    int g = blockIdx.x * 256 + threadIdx.x;
    int co = g / 1152;
    int rem = g - co * 1152;
    int ci = rem / 9, tap = rem - ci * 9;
    wb[((size_t)tap * 128 + co) * 128 + ci] = f2bf(cw[g]);
}

// GEMM weights -> one bf16 buffer (layout preserved [N][K])
__global__ __launch_bounds__(256) void conv_weights(const float* __restrict__ Win,
                                                    const float* __restrict__ in_proj,
                                                    const float* __restrict__ attn_out_w,
                                                    const float* __restrict__ ff1,
                                                    const float* __restrict__ ff2,
                                                    const float* __restrict__ Wout,
                                                    unsigned short* __restrict__ wg) {
    int g = blockIdx.x * 256 + threadIdx.x;      // 589824 total
    float v;
    if      (g < 32768)  v = Win[g];
    else if (g < 229376) v = in_proj[g - 32768];
    else if (g < 294912) v = attn_out_w[g - 229376];
    else if (g < 425984) v = ff1[g - 294912];
    else if (g < 557056) v = ff2[g - 425984];
    else                 v = Wout[g - 557056];
    wg[g] = f2bf(v);
}

// ---------------------------------------------------------------------------
// LayerNorm over E=256, bf16 in -> bf16 out (f32 stats)
__global__ __launch_bounds__(256) void ln_bf16(const unsigned short* __restrict__ in,
                                               unsigned short* __restrict__ out,
                                               const float* __restrict__ w, const float* __restrict__ b) {
    int tok = blockIdx.x * 4 + (threadIdx.x >> 6);
    int lane = threadIdx.x & 63;
    ushort4 h4 = ((const ushort4*)(in + (size_t)tok * 256))[lane];
    float vx = bf2f(h4.x), vy = bf2f(h4.y), vz = bf2f(h4.z), vw = bf2f(h4.w);
    float s = vx + vy + vz + vw;
    #pragma unroll
    for (int off = 32; off > 0; off >>= 1) s += __shfl_xor(s, off);
    float mu = s * (1.0f / 256.0f);
    float dx = vx - mu, dy = vy - mu, dz = vz - mu, dw = vw - mu;
    float vs = dx * dx + dy * dy + dz * dz + dw * dw;
    #pragma unroll
    for (int off = 32; off > 0; off >>= 1) vs += __shfl_xor(vs, off);
    float inv = rsqrtf(vs * (1.0f / 256.0f) + 1e-5f);
    float4 wv = ((const float4*)w)[lane];
    float4 bv = ((const float4*)b)[lane];
    ushort4 o4;
    o4.x = f2bf(dx * inv * wv.x + bv.x);
    o4.y = f2bf(dy * inv * wv.y + bv.y);
    o4.z = f2bf(dz * inv * wv.z + bv.z);
    o4.w = f2bf(dw * inv * wv.w + bv.w);
    *(ushort4*)(out + (size_t)tok * 256 + lane * 4) = o4;
}

// ---------------------------------------------------------------------------
// bf16 MFMA GEMM, 2-phase double-buffered global_load_lds pipeline.
// Y = X[M,K] @ Wt[N,K]^T (+Rb bf16) (relu?) -> Yb bf16.
// spass=1/2: fused scatter epilogue (row -> [slice][pix][ci] layout).
// LDS: linear dest + inverse-swizzled global source; reads use XOR swizzle.
__global__ __launch_bounds__(256) void gemm_bf16(const unsigned short* __restrict__ X,
                                                 const unsigned short* __restrict__ Wt,
                                                 unsigned short* __restrict__ Yb,
                                                 const unsigned short* __restrict__ Rb,
                                                 int N, int K, int relu, int spass, int W) {
    __shared__ unsigned short As[2][128 * 64];
    __shared__ unsigned short Bs[2][128 * 64];
    const int bm = blockIdx.x * 128, bn = blockIdx.y * 128;
    const int tid = threadIdx.x;
    const int lane = tid & 63, w = tid >> 6;
    const int wm = (w >> 1) * 64, wn = (w & 1) * 64;
    const int lr = lane & 15, lq = lane >> 4;
    f32x4 acc[4][4];
    #pragma unroll
    for (int m = 0; m < 4; m++)
        #pragma unroll
        for (int n = 0; n < 4; n++)
            acc[m][n] = (f32x4){0.f, 0.f, 0.f, 0.f};

    // stage one K-tile (BK=64): per wave 4 chunks x 1024B per operand;
    // global col-group = slot ^ (row&7)  (inverse of read-side XOR swizzle)
    const int srow = lane >> 3, sslot = lane & 7;
    auto STAGE = [&](int bsel, int k0) {
        #pragma unroll
        for (int c = 0; c < 4; ++c) {
            int row = (w << 5) + (c << 3) + srow;
            int cg = sslot ^ (row & 7);
            gload_lds16(X  + (size_t)(bm + row) * K + k0 + cg * 8,
                        &As[bsel][(w << 11) + (c << 9)]);
            gload_lds16(Wt + (size_t)(bn + row) * K + k0 + cg * 8,
                        &Bs[bsel][(w << 11) + (c << 9)]);
        }
    };

    const int nt = K >> 6;
    STAGE(0, 0);
    __syncthreads();                      // drains vmcnt(0) per barrier semantics
    int cur = 0;
    for (int t = 0; t < nt; ++t) {
        if (t + 1 < nt) STAGE(cur ^ 1, (t + 1) << 6);
        const char* Ab = (const char*)As[cur];
        const char* Bb = (const char*)Bs[cur];
        #pragma unroll
        for (int ks = 0; ks < 2; ks++) {
            bf16x8 af[4], bf[4];
            #pragma unroll
            for (int m = 0; m < 4; m++) {
                int row = wm + m * 16 + lr;
                int boff = row * 128 + ((ks * 64 + lq * 16) ^ ((row & 7) << 4));
                af[m] = *(const bf16x8*)(Ab + boff);
            }
            #pragma unroll
            for (int n = 0; n < 4; n++) {
                int row = wn + n * 16 + lr;
                int boff = row * 128 + ((ks * 64 + lq * 16) ^ ((row & 7) << 4));
                bf[n] = *(const bf16x8*)(Bb + boff);
            }
            #pragma unroll
            for (int m = 0; m < 4; m++)
                #pragma unroll
                for (int n = 0; n < 4; n++)
                    acc[m][n] = __builtin_amdgcn_mfma_f32_16x16x32_bf16(af[m], bf[n], acc[m][n], 0, 0, 0);
        }
        if (t + 1 < nt) __syncthreads();  // waits stage(t+1) loads + read-done
        cur ^= 1;
    }

    #pragma unroll
    for (int m = 0; m < 4; m++) {
        #pragma unroll
        for (int r = 0; r < 4; r++) {
            int row = bm + wm + m * 16 + lq * 4 + r;
            size_t base;
            if (spass == 0) {
                base = (size_t)row * N;
            } else {
                int l = row / W, c = row - l * W;
                int lb = (c >= 160) ? 1 : 0, sp = c - lb * 160;
                int sl_, pix;
                if (spass == 1) { int u = l >> 5, y = l & 31, v = sp >> 5, x = sp & 31;
                                  sl_ = lb * 25 + u * 5 + v; pix = y * 32 + x; }
                else            { int v = l >> 5, x = l & 31, u = sp >> 5, y = sp & 31;
                                  sl_ = lb * 25 + u * 5 + v; pix = y * 32 + x; }
                base = ((size_t)sl_ * 1024 + pix) * 128;
            }
            #pragma unroll
            for (int n = 0; n < 4; n++) {
                int col = bn + wn + n * 16 + lr;
                float val = acc[m][n][r];
                if (Rb) val += bf2f(Rb[(size_t)row * N + col]);
                if (relu) val = fmaxf(val, 0.0f);
                Yb[base + col] = f2bf(val);
            }
        }
    }
}

// ---------------------------------------------------------------------------
// V transpose: Vtok[t][256] bf16 -> Vt[h][col][d(32)][l(160)] bf16
__global__ __launch_bounds__(256) void vtrans(const unsigned short* __restrict__ vtok,
                                              unsigned short* __restrict__ vt, int W) {
    const int col = blockIdx.x, h = blockIdx.y;
    __shared__ unsigned short t[160][34];
    const int tid = threadIdx.x;
    for (int i = tid; i < 160 * 16; i += 256) {
        int l = i >> 4, dp = i & 15;
        unsigned v = *(const unsigned*)(vtok + ((size_t)l * W + col) * 256 + h * 32 + dp * 2);
        *(unsigned*)&t[l][dp * 2] = v;
    }
    __syncthreads();
    unsigned short* dst = vt + (((size_t)h * W + col) * 32) * 160;
    for (int i = tid; i < 32 * 160; i += 256) {
        int d = i / 160, l = i - d * 160;
        dst[i] = t[l][d];
    }
}

// ---------------------------------------------------------------------------
// MFMA attention (verified round 4/5), bf16 in/out
__global__ __launch_bounds__(64) void attn_mfma(const unsigned short* __restrict__ qk,
                                                const unsigned short* __restrict__ vt,
                                                unsigned short* __restrict__ o, int W) {
    const int col = blockIdx.x;
    const int h = blockIdx.y;
    const int lane = threadIdx.x;
    const int lr = lane & 15, lq = lane >> 4;
    __shared__ __align__(16) unsigned short P_lds[16][168];

    bf16x8 kf[10];
    #pragma unroll
    for (int m = 0; m < 10; m++) {
        size_t t = (size_t)(m * 16 + lr) * W + col;
        kf[m] = *(const bf16x8*)(qk + t * 512 + 256 + h * 32 + lq * 8);
    }
    const unsigned short* vbase = vt + (((size_t)h * W + col) * 32) * 160;
    bf16x8 vf[2][5];
    #pragma unroll
    for (int md = 0; md < 2; md++)
        #pragma unroll
        for (int c = 0; c < 5; c++)
            vf[md][c] = *(const bf16x8*)(vbase + (size_t)(md * 16 + lr) * 160 + c * 32 + lq * 8);

    const float scale = 0.17677669529663687f;
    for (int n = 0; n < 10; n++) {
        const int q = n * 16 + lr;
        bf16x8 qf = *(const bf16x8*)(qk + ((size_t)q * W + col) * 512 + h * 32 + lq * 8);
        f32x4 p[10];
        #pragma unroll
        for (int m = 0; m < 10; m++)
            p[m] = __builtin_amdgcn_mfma_f32_16x16x32_bf16(kf[m], qf, (f32x4){0.f,0.f,0.f,0.f}, 0, 0, 0);
        const int b = lq * 4 - ((n & 1) * 16 + lr);
        float mx = -1e30f;
        #pragma unroll
        for (int m = 0; m < 10; m++) {
            #pragma unroll
            for (int r = 0; r < 4; r++) {
                int dd = b + (m & 1) * 16 + r;
                float s = ((unsigned)(dd + 5) <= 10u) ? p[m][r] : -1e30f;
                p[m][r] = s;
                mx = fmaxf(mx, s);
            }
        }
        mx = fmaxf(mx, __shfl_xor(mx, 16));
        mx = fmaxf(mx, __shfl_xor(mx, 32));
        float sum = 0.f;
        #pragma unroll
        for (int m = 0; m < 10; m++) {
            #pragma unroll
            for (int r = 0; r < 4; r++) {
                float e = __expf((p[m][r] - mx) * scale);
                p[m][r] = e;
                sum += e;
            }
        }
        sum += __shfl_xor(sum, 16);
        sum += __shfl_xor(sum, 32);
        #pragma unroll
        for (int m = 0; m < 10; m++) {
            ushort4 pk;
            pk.x = f2bf(p[m][0]); pk.y = f2bf(p[m][1]);
            pk.z = f2bf(p[m][2]); pk.w = f2bf(p[m][3]);
            *(ushort4*)&P_lds[lr][m * 16 + lq * 4] = pk;
        }
        f32x4 oa0 = (f32x4){0.f,0.f,0.f,0.f}, oa1 = (f32x4){0.f,0.f,0.f,0.f};
        #pragma unroll
        for (int c = 0; c < 5; c++) {
            bf16x8 pf = *(const bf16x8*)&P_lds[lr][c * 32 + lq * 8];
            oa0 = __builtin_amdgcn_mfma_f32_16x16x32_bf16(vf[0][c], pf, oa0, 0, 0, 0);
            oa1 = __builtin_amdgcn_mfma_f32_16x16x32_bf16(vf[1][c], pf, oa1, 0, 0, 0);
        }
        const float inv = 1.0f / sum;
        unsigned short* op = o + ((size_t)q * W + col) * 256 + h * 32;
        ushort4 s0, s1;
        s0.x = f2bf(oa0[0] * inv); s0.y = f2bf(oa0[1] * inv);
        s0.z = f2bf(oa0[2] * inv); s0.w = f2bf(oa0[3] * inv);
        s1.x = f2bf(oa1[0] * inv); s1.y = f2bf(oa1[1] * inv);
        s1.z = f2bf(oa1[2] * inv); s1.w = f2bf(oa1[3] * inv);
        *(ushort4*)(op + lq * 4)      = s0;
        *(ushort4*)(op + 16 + lq * 4) = s1;
    }
}

// ---------------------------------------------------------------------------
// conv as implicit MFMA GEMM (verified round 3)
__global__ __launch_bounds__(256) void conv_mfma(const unsigned short* __restrict__ xp,
                                                 const unsigned short* __restrict__ wb,
                                                 const float* __restrict__ res,
                                                 float* __restrict__ out, int bb0) {
    const int ptile = blockIdx.x;
    const int slice = blockIdx.y;
    const int lb = slice / 25, n = slice % 25;
    const int bb = bb0 + lb;
    const int y0 = ptile * 4;
    __shared__ unsigned short As[128 * 64];
    __shared__ unsigned short Bs[128 * 64];
    const int tid = threadIdx.x;
    const int lane = tid & 63, w = tid >> 6;
    const int wm = (w >> 1) * 64;
    const int wn = (w & 1) * 64;
    const int lr = lane & 15, lq = lane >> 4;
    const unsigned short* xs = xp + (size_t)slice * 1024 * 128;
    f32x4 acc[4][4];
    #pragma unroll
    for (int m = 0; m < 4; m++)
        #pragma unroll
        for (int nn = 0; nn < 4; nn++)
            acc[m][nn] = (f32x4){0.f, 0.f, 0.f, 0.f};

    for (int tap = 0; tap < 9; tap++) {
        const int dy = tap / 3 - 1, dx = tap % 3 - 1;
        for (int c0 = 0; c0 < 128; c0 += 64) {
            #pragma unroll
            for (int i = 0; i < 4; i++) {
                int id = tid + 256 * i;
                int row = id >> 3, cg = id & 7;
                int py = y0 + (row >> 5) + dy;
                int px = (row & 31) + dx;
                uint4 v = {0u, 0u, 0u, 0u};
                if ((unsigned)py < 32u && (unsigned)px < 32u)
                    v = *(const uint4*)(xs + ((size_t)(py * 32 + px) * 128 + c0 + cg * 8));
                int boff = row * 128 + ((cg * 16) ^ ((row & 7) << 4));
                *(uint4*)((char*)As + boff) = v;
            }
            #pragma unroll
            for (int i = 0; i < 4; i++) {
                int id = tid + 256 * i;
                int row = id >> 3, cg = id & 7;
                uint4 v = *(const uint4*)(wb + (((size_t)tap * 128 + row) * 128 + c0 + cg * 8));
                int boff = row * 128 + ((cg * 16) ^ ((row & 7) << 4));
                *(uint4*)((char*)Bs + boff) = v;
            }
            __syncthreads();
            #pragma unroll
            for (int ks = 0; ks < 2; ks++) {
                bf16x8 wf[4], xf[4];
                #pragma unroll
                for (int m = 0; m < 4; m++) {
                    int row = wm + m * 16 + lr;
                    int boff = row * 128 + ((ks * 64 + lq * 16) ^ ((row & 7) << 4));
                    wf[m] = *(const bf16x8*)((const char*)Bs + boff);
                }
                #pragma unroll
                for (int nn = 0; nn < 4; nn++) {
                    int row = wn + nn * 16 + lr;
                    int boff = row * 128 + ((ks * 64 + lq * 16) ^ ((row & 7) << 4));
                    xf[nn] = *(const bf16x8*)((const char*)As + boff);
                }
                #pragma unroll
                for (int m = 0; m < 4; m++)
                    #pragma unroll
                    for (int nn = 0; nn < 4; nn++)
                        acc[m][nn] = __builtin_amdgcn_mfma_f32_16x16x32_bf16(wf[m], xf[nn], acc[m][nn], 0, 0, 0);
            }
            __syncthreads();
        }
    }
    #pragma unroll
    for (int m = 0; m < 4; m++) {
        int co0 = wm + m * 16 + lq * 4;
        #pragma unroll
        for (int r = 0; r < 4; r++) {
            size_t rowoff = (((size_t)(bb * 128 + co0 + r) * 25 + n) * 1024) + ptile * 128;
            #pragma unroll
            for (int nn = 0; nn < 4; nn++) {
                int pix = wn + nn * 16 + lr;
                out[rowoff + pix] = acc[m][nn][r] + res[rowoff + pix];
            }
        }
    }
}

// ---------------------------------------------------------------------------
extern "C" void kernel_launch(void* const* d_in, const int* in_sizes, int n_in,
                              void* d_out, int out_size, void* d_ws, size_t ws_size,
                              hipStream_t stream) {
    (void)in_sizes; (void)n_in; (void)out_size;
    const float* buffer     = (const float*)d_in[0];
    const float* Win        = (const float*)d_in[1];
    const float* ln_w       = (const float*)d_in[2];
    const float* ln_b       = (const float*)d_in[3];
    const float* in_proj    = (const float*)d_in[4];
    const float* attn_out_w = (const float*)d_in[5];
    const float* ffn_ln_w   = (const float*)d_in[6];
    const float* ffn_ln_b   = (const float*)d_in[7];
    const float* ff1        = (const float*)d_in[8];
    const float* ff2        = (const float*)d_in[9];
    const float* Wout       = (const float*)d_in[10];
    const float* conv_w     = (const float*)d_in[11];
    float* out = (float*)d_out;
    float* ws  = (float*)d_ws;

    // bf16 layout needs T*960 floats + 368640 floats of weights.
    // NBB=2 (T=51200) -> ~198 MB; d_ws is 256 MiB -> single-chunk mode.
    const size_t need2 = ((size_t)51200 * 960 + 368640) * 4;
    int NBB = (ws_size >= need2) ? 2 : 1;
    const int W = NBB * 160;
    const size_t T = (size_t)NBB * 25600;

    // layout (float-slot offsets); all bf16
    unsigned short* x0b   = (unsigned short*)ws;                 // T*128 bf16
    unsigned short* Abf   = (unsigned short*)(ws + T * 64);      // T*256 bf16 residual
    unsigned short* tnb   = (unsigned short*)(ws + T * 192);     // T*256 bf16
    float*          C     = ws + T * 320;                        // T*512 fl region
    unsigned short* QKtok = (unsigned short*)C;                  // T*512 bf16
    unsigned short* Vtok  = (unsigned short*)(C + T * 256);      // T*256 bf16
    unsigned short* Vt    = (unsigned short*)(C + T * 384);      // T*256 bf16
    unsigned short* hidb  = (unsigned short*)C;                  // T*512 bf16 (QK dead)
    unsigned short* xp    = (unsigned short*)C;                  // T*128 bf16 (hid dead)
    unsigned short* Db    = (unsigned short*)(ws + T * 832);     // T*256 bf16
    unsigned short* wg    = (unsigned short*)(ws + T * 960);     // 589824 bf16
    unsigned short* wb    = (unsigned short*)(ws + T * 960 + 294912); // 147456 bf16

    const unsigned short* Winb  = wg;
    const unsigned short* Wqkb  = wg + 32768;
    const unsigned short* Wvb   = wg + 32768 + 512 * 256;
    const unsigned short* Waob  = wg + 229376;
    const unsigned short* Wff1b = wg + 294912;
    const unsigned short* Wff2b = wg + 425984;
    const unsigned short* Woutb = wg + 557056;

    const int GM = (int)(T / 128);

    conv_weights<<<2304, 256, 0, stream>>>(Win, in_proj, attn_out_w, ff1, ff2, Wout, wg);
    repack_w<<<576, 256, 0, stream>>>(conv_w, wb);

    for (int pass = 0; pass < 2; pass++) {
        const float* src = (pass == 0) ? buffer : out;
        for (int bb0 = 0; bb0 < 2; bb0 += NBB) {
            if (pass == 0) gather1<<<dim3(128, 25, NBB), 256, 0, stream>>>(src, x0b, W, bb0);
            else           gather2<<<dim3(128, 25, NBB), 256, 0, stream>>>(src, x0b, W, bb0);

            // tok = x0 @ Win^T (K=128) -> Abf
            gemm_bf16<<<dim3(GM, 2), 256, 0, stream>>>(x0b, Winb, Abf, nullptr, 256, 128, 0, 0, W);
            ln_bf16<<<(int)(T / 4), 256, 0, stream>>>(Abf, tnb, ln_w, ln_b);
            // qk = tn @ [Wq;Wk]^T (N=512)
            gemm_bf16<<<dim3(GM, 4), 256, 0, stream>>>(tnb, Wqkb, QKtok, nullptr, 512, 256, 0, 0, W);
            // vv = tok @ Wv^T
            gemm_bf16<<<dim3(GM, 2), 256, 0, stream>>>(Abf, Wvb, Vtok, nullptr, 256, 256, 0, 0, W);
            vtrans<<<dim3(W, 8), 256, 0, stream>>>(Vtok, Vt, W);
            attn_mfma<<<dim3(W, 8), 64, 0, stream>>>(QKtok, Vt, Db, W);
            // tok += ob @ attn_out_w^T  (in-place bf16 residual)
            gemm_bf16<<<dim3(GM, 2), 256, 0, stream>>>(Db, Waob, Abf, Abf, 256, 256, 0, 0, W);
            ln_bf16<<<(int)(T / 4), 256, 0, stream>>>(Abf, tnb, ffn_ln_w, ffn_ln_b);
            // hidden = relu(tn2 @ ff1^T) (N=512)
            gemm_bf16<<<dim3(GM, 4), 256, 0, stream>>>(tnb, Wff1b, hidb, nullptr, 512, 256, 1, 0, W);
            // tok += hidden @ ff2^T (K=512, in-place residual)
            gemm_bf16<<<dim3(GM, 2), 256, 0, stream>>>(hidb, Wff2b, Abf, Abf, 256, 512, 0, 0, W);
            // ot = tok @ Wout^T (N=128) -> fused scatter into xp (pixel-major)
            gemm_bf16<<<dim3(GM, 1), 256, 0, stream>>>(Abf, Woutb, xp, nullptr, 128, 256, 0, pass + 1, W);

            conv_mfma<<<dim3(8, NBB * 25), 256, 0, stream>>>(
                xp, wb, (pass == 0) ? buffer : (const float*)out, out, bb0);
        }
    }
}

// Round 9
// 658.596 us; speedup vs baseline: 6.5449x; 1.0479x over previous
//
#include <hip/hip_runtime.h>
#include <math.h>
#include <stdint.h>

typedef __attribute__((ext_vector_type(8))) short bf16x8;
typedef __attribute__((ext_vector_type(4))) float f32x4;

static __device__ __forceinline__ unsigned short f2bf(float f) {
    unsigned u = __builtin_bit_cast(unsigned, f);
    unsigned r = u + 0x7fffu + ((u >> 16) & 1u);   // RNE
    return (unsigned short)(r >> 16);
}
static __device__ __forceinline__ float bf2f(unsigned short h) {
    return __builtin_bit_cast(float, ((unsigned)h) << 16);
}
// async global->LDS, 16B per lane; lds dest = uniform base + lane*16
static __device__ __forceinline__ void gload_lds16(const void* g, void* l) {
    __builtin_amdgcn_global_load_lds((const __attribute__((address_space(1))) unsigned int*)g,
                                     (__attribute__((address_space(3))) unsigned int*)l, 16, 0, 0);
}

// ---------------------------------------------------------------------------
// gather pass1: x0b[t'][cc] (bf16) = src[bb][cc][u*5+v][y][x]
__global__ __launch_bounds__(256) void gather1(const float* __restrict__ src,
                                               unsigned short* __restrict__ x0, int W, int bb0) {
    int cct = blockIdx.x & 3, y = blockIdx.x >> 2;
    int n = blockIdx.y; int u = n / 5, v = n % 5;
    int lb = blockIdx.z, bb = bb0 + lb;
    __shared__ float tile[32][33];
    int tx = threadIdx.x & 31, tg = threadIdx.x >> 5;
    const float* s = src + (((size_t)(bb * 128 + cct * 32) * 25 + n) * 32 + y) * 32;
    #pragma unroll
    for (int i = 0; i < 4; i++) {
        int cl = tg + 8 * i;
        tile[cl][tx] = s[(size_t)cl * 25600 + tx];
    }
    __syncthreads();
    unsigned short* d = x0 + ((size_t)(u * 32 + y) * W + lb * 160 + v * 32) * 128 + cct * 32;
    #pragma unroll
    for (int i = 0; i < 4; i++) {
        int xx = tg + 8 * i;
        d[(size_t)xx * 128 + tx] = f2bf(tile[tx][xx]);
    }
}

// gather pass2
__global__ __launch_bounds__(256) void gather2(const float* __restrict__ src,
                                               unsigned short* __restrict__ x0, int W, int bb0) {
    int cct = blockIdx.x & 3, x = blockIdx.x >> 2;
    int n = blockIdx.y; int u = n / 5, v = n % 5;
    int lb = blockIdx.z, bb = bb0 + lb;
    __shared__ float tile[32][33];
    int tx = threadIdx.x & 31, tg = threadIdx.x >> 5;
    const float* s = src + (((size_t)(bb * 128 + cct * 32) * 25 + n) * 32) * 32 + x;
    #pragma unroll
    for (int i = 0; i < 4; i++) {
        int cl = tg + 8 * i;
        tile[cl][tx] = s[(size_t)cl * 25600 + tx * 32];
    }
    __syncthreads();
    unsigned short* d = x0 + ((size_t)(v * 32 + x) * W + lb * 160 + u * 32) * 128 + cct * 32;
    #pragma unroll
    for (int i = 0; i < 4; i++) {
        int yy = tg + 8 * i;
        d[(size_t)yy * 128 + tx] = f2bf(tile[tx][yy]);
    }
}

// ---------------------------------------------------------------------------
// conv weight repack: conv_w[co][ci][tap(9)] f32 -> wb[tap][co][ci] bf16
__global__ __launch_bounds__(256) void repack_w(const float* __restrict__ cw,
                                                unsigned short* __restrict__ wb) {
    int g = blockIdx.x * 256 + threadIdx.x;
    int co = g / 1152;
    int rem = g - co * 1152;
    int ci = rem / 9, tap = rem - ci * 9;
    wb[((size_t)tap * 128 + co) * 128 + ci] = f2bf(cw[g]);
}

// GEMM weights -> one bf16 buffer (layout preserved [N][K])
__global__ __launch_bounds__(256) void conv_weights(const float* __restrict__ Win,
                                                    const float* __restrict__ in_proj,
                                                    const float* __restrict__ attn_out_w,
                                                    const float* __restrict__ ff1,
                                                    const float* __restrict__ ff2,
                                                    const float* __restrict__ Wout,
                                                    unsigned short* __restrict__ wg) {
    int g = blockIdx.x * 256 + threadIdx.x;      // 589824 total
    float v;
    if      (g < 32768)  v = Win[g];
    else if (g < 229376) v = in_proj[g - 32768];
    else if (g < 294912) v = attn_out_w[g - 229376];
    else if (g < 425984) v = ff1[g - 294912];
    else if (g < 557056) v = ff2[g - 425984];
    else                 v = Wout[g - 557056];
    wg[g] = f2bf(v);
}

// ---------------------------------------------------------------------------
// LayerNorm over E=256, bf16 in -> bf16 out (f32 stats)
__global__ __launch_bounds__(256) void ln_bf16(const unsigned short* __restrict__ in,
                                               unsigned short* __restrict__ out,
                                               const float* __restrict__ w, const float* __restrict__ b) {
    int tok = blockIdx.x * 4 + (threadIdx.x >> 6);
    int lane = threadIdx.x & 63;
    ushort4 h4 = ((const ushort4*)(in + (size_t)tok * 256))[lane];
    float vx = bf2f(h4.x), vy = bf2f(h4.y), vz = bf2f(h4.z), vw = bf2f(h4.w);
    float s = vx + vy + vz + vw;
    #pragma unroll
    for (int off = 32; off > 0; off >>= 1) s += __shfl_xor(s, off);
    float mu = s * (1.0f / 256.0f);
    float dx = vx - mu, dy = vy - mu, dz = vz - mu, dw = vw - mu;
    float vs = dx * dx + dy * dy + dz * dz + dw * dw;
    #pragma unroll
    for (int off = 32; off > 0; off >>= 1) vs += __shfl_xor(vs, off);
    float inv = rsqrtf(vs * (1.0f / 256.0f) + 1e-5f);
    float4 wv = ((const float4*)w)[lane];
    float4 bv = ((const float4*)b)[lane];
    ushort4 o4;
    o4.x = f2bf(dx * inv * wv.x + bv.x);
    o4.y = f2bf(dy * inv * wv.y + bv.y);
    o4.z = f2bf(dz * inv * wv.z + bv.z);
    o4.w = f2bf(dw * inv * wv.w + bv.w);
    *(ushort4*)(out + (size_t)tok * 256 + lane * 4) = o4;
}

// ---------------------------------------------------------------------------
// GEMM core: 128x128 tile, BK=32 double-buffered global_load_lds pipeline.
// LDS per buffer: A 8KB + B 8KB -> 32KB total -> 5 blocks/CU.
// Row = 64B; 16B-slot swizzle: slot ^= (row&3), applied on staging source
// and on ds_read. Leaves a 4-way LDS read conflict (not critical path).
static __device__ __forceinline__ void gemm_core(const unsigned short* __restrict__ X,
                                                 const unsigned short* __restrict__ Wt,
                                                 int bm, int bnrow, int K,
                                                 unsigned short (&As)[2][128 * 32],
                                                 unsigned short (&Bs)[2][128 * 32],
                                                 f32x4 (&acc)[4][4]) {
    const int tid = threadIdx.x;
    const int lane = tid & 63, w = tid >> 6;
    const int wm = (w >> 1) * 64, wn = (w & 1) * 64;
    const int lr = lane & 15, lq = lane >> 4;
    #pragma unroll
    for (int m = 0; m < 4; m++)
        #pragma unroll
        for (int n = 0; n < 4; n++)
            acc[m][n] = (f32x4){0.f, 0.f, 0.f, 0.f};

    const int srow = lane >> 2, sslot = lane & 3;   // 16 rows/KB chunk
    auto STAGE = [&](int bsel, int k0) {
        #pragma unroll
        for (int c = 0; c < 2; ++c) {
            int row = (w << 5) + (c << 4) + srow;   // 32 rows per wave
            int sl = sslot ^ (row & 3);
            gload_lds16(X  + (size_t)(bm + row) * K + k0 + sl * 8,
                        &As[bsel][(w << 10) + (c << 9)]);
            gload_lds16(Wt + (size_t)(bnrow + row) * K + k0 + sl * 8,
                        &Bs[bsel][(w << 10) + (c << 9)]);
        }
    };

    const int nt = K >> 5;
    STAGE(0, 0);
    __syncthreads();
    int cur = 0;
    for (int t = 0; t < nt; ++t) {
        if (t + 1 < nt) STAGE(cur ^ 1, (t + 1) << 5);
        const char* Ab = (const char*)As[cur];
        const char* Bb = (const char*)Bs[cur];
        bf16x8 af[4], bf[4];
        #pragma unroll
        for (int m = 0; m < 4; m++) {
            int row = wm + m * 16 + lr;
            af[m] = *(const bf16x8*)(Ab + row * 64 + ((lq * 16) ^ ((row & 3) << 4)));
        }
        #pragma unroll
        for (int n = 0; n < 4; n++) {
            int row = wn + n * 16 + lr;
            bf[n] = *(const bf16x8*)(Bb + row * 64 + ((lq * 16) ^ ((row & 3) << 4)));
        }
        #pragma unroll
        for (int m = 0; m < 4; m++)
            #pragma unroll
            for (int n = 0; n < 4; n++)
                acc[m][n] = __builtin_amdgcn_mfma_f32_16x16x32_bf16(af[m], bf[n], acc[m][n], 0, 0, 0);
        if (t + 1 < nt) __syncthreads();
        cur ^= 1;
    }
}

// general GEMM: Y = X @ Wt^T (+Rb) (relu?), spass=1/2 fused scatter epilogue
__global__ __launch_bounds__(256) void gemm_bf16(const unsigned short* __restrict__ X,
                                                 const unsigned short* __restrict__ Wt,
                                                 unsigned short* __restrict__ Yb,
                                                 const unsigned short* __restrict__ Rb,
                                                 int N, int K, int relu, int spass, int W) {
    __shared__ unsigned short As[2][128 * 32];
    __shared__ unsigned short Bs[2][128 * 32];
    const int bm = blockIdx.x * 128, bn = blockIdx.y * 128;
    f32x4 acc[4][4];
    gemm_core(X, Wt, bm, bn, K, As, Bs, acc);

    const int lane = threadIdx.x & 63, w = threadIdx.x >> 6;
    const int wm = (w >> 1) * 64, wn = (w & 1) * 64;
    const int lr = lane & 15, lq = lane >> 4;
    #pragma unroll
    for (int m = 0; m < 4; m++) {
        #pragma unroll
        for (int r = 0; r < 4; r++) {
            int row = bm + wm + m * 16 + lq * 4 + r;
            size_t base;
            if (spass == 0) {
                base = (size_t)row * N;
            } else {
                int l = row / W, c = row - l * W;
                int lb = (c >= 160) ? 1 : 0, sp = c - lb * 160;
                int sl_, pix;
                if (spass == 1) { int u = l >> 5, y = l & 31, v = sp >> 5, x = sp & 31;
                                  sl_ = lb * 25 + u * 5 + v; pix = y * 32 + x; }
                else            { int v = l >> 5, x = l & 31, u = sp >> 5, y = sp & 31;
                                  sl_ = lb * 25 + u * 5 + v; pix = y * 32 + x; }
                base = ((size_t)sl_ * 1024 + pix) * 128;
            }
            #pragma unroll
            for (int n = 0; n < 4; n++) {
                int col = bn + wn + n * 16 + lr;
                float val = acc[m][n][r];
                if (Rb) val += bf2f(Rb[(size_t)row * N + col]);
                if (relu) val = fmaxf(val, 0.0f);
                Yb[base + col] = f2bf(val);
            }
        }
    }
}

// fused qk+v GEMM: in_proj rows [0..767] = [Wq;Wk;Wv] contiguous, K=256.
// by 0..3: QK = tn @ rows[by*128..], out QKtok (N=512).
// by 4..5: V  = tok @ rows[by*128..], out Vtok (N=256).
__global__ __launch_bounds__(256) void gemm_qkv(const unsigned short* __restrict__ tn,
                                                const unsigned short* __restrict__ tok,
                                                const unsigned short* __restrict__ Wqkv,
                                                unsigned short* __restrict__ QK,
                                                unsigned short* __restrict__ V) {
    __shared__ unsigned short As[2][128 * 32];
    __shared__ unsigned short Bs[2][128 * 32];
    const int bm = blockIdx.x * 128, by = blockIdx.y;
    const unsigned short* X = (by < 4) ? tn : tok;
    f32x4 acc[4][4];
    gemm_core(X, Wqkv, bm, by * 128, 256, As, Bs, acc);

    unsigned short* Yb = (by < 4) ? QK : V;
    const int N = (by < 4) ? 512 : 256;
    const int bn = (by < 4) ? by * 128 : (by - 4) * 128;
    const int lane = threadIdx.x & 63, w = threadIdx.x >> 6;
    const int wm = (w >> 1) * 64, wn = (w & 1) * 64;
    const int lr = lane & 15, lq = lane >> 4;
    #pragma unroll
    for (int m = 0; m < 4; m++) {
        #pragma unroll
        for (int r = 0; r < 4; r++) {
            int row = bm + wm + m * 16 + lq * 4 + r;
            #pragma unroll
            for (int n = 0; n < 4; n++) {
                int col = bn + wn + n * 16 + lr;
                Yb[(size_t)row * N + col] = f2bf(acc[m][n][r]);
            }
        }
    }
}

// ---------------------------------------------------------------------------
// V transpose: Vtok[t][256] bf16 -> Vt[h][col][d(32)][l(160)] bf16
__global__ __launch_bounds__(256) void vtrans(const unsigned short* __restrict__ vtok,
                                              unsigned short* __restrict__ vt, int W) {
    const int col = blockIdx.x, h = blockIdx.y;
    __shared__ unsigned short t[160][34];
    const int tid = threadIdx.x;
    for (int i = tid; i < 160 * 16; i += 256) {
        int l = i >> 4, dp = i & 15;
        unsigned v = *(const unsigned*)(vtok + ((size_t)l * W + col) * 256 + h * 32 + dp * 2);
        *(unsigned*)&t[l][dp * 2] = v;
    }
    __syncthreads();
    unsigned short* dst = vt + (((size_t)h * W + col) * 32) * 160;
    for (int i = tid; i < 32 * 160; i += 256) {
        int d = i / 160, l = i - d * 160;
        dst[i] = t[l][d];
    }
}

// ---------------------------------------------------------------------------
// MFMA attention (verified round 4/5), bf16 in/out
__global__ __launch_bounds__(64) void attn_mfma(const unsigned short* __restrict__ qk,
                                                const unsigned short* __restrict__ vt,
                                                unsigned short* __restrict__ o, int W) {
    const int col = blockIdx.x;
    const int h = blockIdx.y;
    const int lane = threadIdx.x;
    const int lr = lane & 15, lq = lane >> 4;
    __shared__ __align__(16) unsigned short P_lds[16][168];

    bf16x8 kf[10];
    #pragma unroll
    for (int m = 0; m < 10; m++) {
        size_t t = (size_t)(m * 16 + lr) * W + col;
        kf[m] = *(const bf16x8*)(qk + t * 512 + 256 + h * 32 + lq * 8);
    }
    const unsigned short* vbase = vt + (((size_t)h * W + col) * 32) * 160;
    bf16x8 vf[2][5];
    #pragma unroll
    for (int md = 0; md < 2; md++)
        #pragma unroll
        for (int c = 0; c < 5; c++)
            vf[md][c] = *(const bf16x8*)(vbase + (size_t)(md * 16 + lr) * 160 + c * 32 + lq * 8);

    const float scale = 0.17677669529663687f;
    for (int n = 0; n < 10; n++) {
        const int q = n * 16 + lr;
        bf16x8 qf = *(const bf16x8*)(qk + ((size_t)q * W + col) * 512 + h * 32 + lq * 8);
        f32x4 p[10];
        #pragma unroll
        for (int m = 0; m < 10; m++)
            p[m] = __builtin_amdgcn_mfma_f32_16x16x32_bf16(kf[m], qf, (f32x4){0.f,0.f,0.f,0.f}, 0, 0, 0);
        const int b = lq * 4 - ((n & 1) * 16 + lr);
        float mx = -1e30f;
        #pragma unroll
        for (int m = 0; m < 10; m++) {
            #pragma unroll
            for (int r = 0; r < 4; r++) {
                int dd = b + (m & 1) * 16 + r;
                float s = ((unsigned)(dd + 5) <= 10u) ? p[m][r] : -1e30f;
                p[m][r] = s;
                mx = fmaxf(mx, s);
            }
        }
        mx = fmaxf(mx, __shfl_xor(mx, 16));
        mx = fmaxf(mx, __shfl_xor(mx, 32));
        float sum = 0.f;
        #pragma unroll
        for (int m = 0; m < 10; m++) {
            #pragma unroll
            for (int r = 0; r < 4; r++) {
                float e = __expf((p[m][r] - mx) * scale);
                p[m][r] = e;
                sum += e;
            }
        }
        sum += __shfl_xor(sum, 16);
        sum += __shfl_xor(sum, 32);
        #pragma unroll
        for (int m = 0; m < 10; m++) {
            ushort4 pk;
            pk.x = f2bf(p[m][0]); pk.y = f2bf(p[m][1]);
            pk.z = f2bf(p[m][2]); pk.w = f2bf(p[m][3]);
            *(ushort4*)&P_lds[lr][m * 16 + lq * 4] = pk;
        }
        f32x4 oa0 = (f32x4){0.f,0.f,0.f,0.f}, oa1 = (f32x4){0.f,0.f,0.f,0.f};
        #pragma unroll
        for (int c = 0; c < 5; c++) {
            bf16x8 pf = *(const bf16x8*)&P_lds[lr][c * 32 + lq * 8];
            oa0 = __builtin_amdgcn_mfma_f32_16x16x32_bf16(vf[0][c], pf, oa0, 0, 0, 0);
            oa1 = __builtin_amdgcn_mfma_f32_16x16x32_bf16(vf[1][c], pf, oa1, 0, 0, 0);
        }
        const float inv = 1.0f / sum;
        unsigned short* op = o + ((size_t)q * W + col) * 256 + h * 32;
        ushort4 s0, s1;
        s0.x = f2bf(oa0[0] * inv); s0.y = f2bf(oa0[1] * inv);
        s0.z = f2bf(oa0[2] * inv); s0.w = f2bf(oa0[3] * inv);
        s1.x = f2bf(oa1[0] * inv); s1.y = f2bf(oa1[1] * inv);
        s1.z = f2bf(oa1[2] * inv); s1.w = f2bf(oa1[3] * inv);
        *(ushort4*)(op + lq * 4)      = s0;
        *(ushort4*)(op + 16 + lq * 4) = s1;
    }
}

// ---------------------------------------------------------------------------
// conv as implicit MFMA GEMM (verified round 3)
__global__ __launch_bounds__(256) void conv_mfma(const unsigned short* __restrict__ xp,
                                                 const unsigned short* __restrict__ wb,
                                                 const float* __restrict__ res,
                                                 float* __restrict__ out, int bb0) {
    const int ptile = blockIdx.x;
    const int slice = blockIdx.y;
    const int lb = slice / 25, n = slice % 25;
    const int bb = bb0 + lb;
    const int y0 = ptile * 4;
    __shared__ unsigned short As[128 * 64];
    __shared__ unsigned short Bs[128 * 64];
    const int tid = threadIdx.x;
    const int lane = tid & 63, w = tid >> 6;
    const int wm = (w >> 1) * 64;
    const int wn = (w & 1) * 64;
    const int lr = lane & 15, lq = lane >> 4;
    const unsigned short* xs = xp + (size_t)slice * 1024 * 128;
    f32x4 acc[4][4];
    #pragma unroll
    for (int m = 0; m < 4; m++)
        #pragma unroll
        for (int nn = 0; nn < 4; nn++)
            acc[m][nn] = (f32x4){0.f, 0.f, 0.f, 0.f};

    for (int tap = 0; tap < 9; tap++) {
        const int dy = tap / 3 - 1, dx = tap % 3 - 1;
        for (int c0 = 0; c0 < 128; c0 += 64) {
            #pragma unroll
            for (int i = 0; i < 4; i++) {
                int id = tid + 256 * i;
                int row = id >> 3, cg = id & 7;
                int py = y0 + (row >> 5) + dy;
                int px = (row & 31) + dx;
                uint4 v = {0u, 0u, 0u, 0u};
                if ((unsigned)py < 32u && (unsigned)px < 32u)
                    v = *(const uint4*)(xs + ((size_t)(py * 32 + px) * 128 + c0 + cg * 8));
                int boff = row * 128 + ((cg * 16) ^ ((row & 7) << 4));
                *(uint4*)((char*)As + boff) = v;
            }
            #pragma unroll
            for (int i = 0; i < 4; i++) {
                int id = tid + 256 * i;
                int row = id >> 3, cg = id & 7;
                uint4 v = *(const uint4*)(wb + (((size_t)tap * 128 + row) * 128 + c0 + cg * 8));
                int boff = row * 128 + ((cg * 16) ^ ((row & 7) << 4));
                *(uint4*)((char*)Bs + boff) = v;
            }
            __syncthreads();
            #pragma unroll
            for (int ks = 0; ks < 2; ks++) {
                bf16x8 wf[4], xf[4];
                #pragma unroll
                for (int m = 0; m < 4; m++) {
                    int row = wm + m * 16 + lr;
                    int boff = row * 128 + ((ks * 64 + lq * 16) ^ ((row & 7) << 4));
                    wf[m] = *(const bf16x8*)((const char*)Bs + boff);
                }
                #pragma unroll
                for (int nn = 0; nn < 4; nn++) {
                    int row = wn + nn * 16 + lr;
                    int boff = row * 128 + ((ks * 64 + lq * 16) ^ ((row & 7) << 4));
                    xf[nn] = *(const bf16x8*)((const char*)As + boff);
                }
                #pragma unroll
                for (int m = 0; m < 4; m++)
                    #pragma unroll
                    for (int nn = 0; nn < 4; nn++)
                        acc[m][nn] = __builtin_amdgcn_mfma_f32_16x16x32_bf16(wf[m], xf[nn], acc[m][nn], 0, 0, 0);
            }
            __syncthreads();
        }
    }
    #pragma unroll
    for (int m = 0; m < 4; m++) {
        int co0 = wm + m * 16 + lq * 4;
        #pragma unroll
        for (int r = 0; r < 4; r++) {
            size_t rowoff = (((size_t)(bb * 128 + co0 + r) * 25 + n) * 1024) + ptile * 128;
            #pragma unroll
            for (int nn = 0; nn < 4; nn++) {
                int pix = wn + nn * 16 + lr;
                out[rowoff + pix] = acc[m][nn][r] + res[rowoff + pix];
            }
        }
    }
}

// ---------------------------------------------------------------------------
extern "C" void kernel_launch(void* const* d_in, const int* in_sizes, int n_in,
                              void* d_out, int out_size, void* d_ws, size_t ws_size,
                              hipStream_t stream) {
    (void)in_sizes; (void)n_in; (void)out_size;
    const float* buffer     = (const float*)d_in[0];
    const float* Win        = (const float*)d_in[1];
    const float* ln_w       = (const float*)d_in[2];
    const float* ln_b       = (const float*)d_in[3];
    const float* in_proj    = (const float*)d_in[4];
    const float* attn_out_w = (const float*)d_in[5];
    const float* ffn_ln_w   = (const float*)d_in[6];
    const float* ffn_ln_b   = (const float*)d_in[7];
    const float* ff1        = (const float*)d_in[8];
    const float* ff2        = (const float*)d_in[9];
    const float* Wout       = (const float*)d_in[10];
    const float* conv_w     = (const float*)d_in[11];
    float* out = (float*)d_out;
    float* ws  = (float*)d_ws;

    const size_t need2 = ((size_t)51200 * 960 + 368640) * 4;
    int NBB = (ws_size >= need2) ? 2 : 1;
    const int W = NBB * 160;
    const size_t T = (size_t)NBB * 25600;

    // layout (float-slot offsets); all bf16
    unsigned short* x0b   = (unsigned short*)ws;                 // T*128 bf16
    unsigned short* Abf   = (unsigned short*)(ws + T * 64);      // T*256 bf16 residual
    unsigned short* tnb   = (unsigned short*)(ws + T * 192);     // T*256 bf16
    float*          C     = ws + T * 320;                        // T*512 fl region
    unsigned short* QKtok = (unsigned short*)C;                  // T*512 bf16
    unsigned short* Vtok  = (unsigned short*)(C + T * 256);      // T*256 bf16
    unsigned short* Vt    = (unsigned short*)(C + T * 384);      // T*256 bf16
    unsigned short* hidb  = (unsigned short*)C;                  // T*512 bf16 (QK dead)
    unsigned short* xp    = (unsigned short*)C;                  // T*128 bf16 (hid dead)
    unsigned short* Db    = (unsigned short*)(ws + T * 832);     // T*256 bf16
    unsigned short* wg    = (unsigned short*)(ws + T * 960);     // 589824 bf16
    unsigned short* wb    = (unsigned short*)(ws + T * 960 + 294912); // 147456 bf16

    const unsigned short* Winb  = wg;
    const unsigned short* Wqkvb = wg + 32768;            // 768 rows: [Wq;Wk;Wv]
    const unsigned short* Waob  = wg + 229376;
    const unsigned short* Wff1b = wg + 294912;
    const unsigned short* Wff2b = wg + 425984;
    const unsigned short* Woutb = wg + 557056;

    const int GM = (int)(T / 128);

    conv_weights<<<2304, 256, 0, stream>>>(Win, in_proj, attn_out_w, ff1, ff2, Wout, wg);
    repack_w<<<576, 256, 0, stream>>>(conv_w, wb);

    for (int pass = 0; pass < 2; pass++) {
        const float* src = (pass == 0) ? buffer : out;
        for (int bb0 = 0; bb0 < 2; bb0 += NBB) {
            if (pass == 0) gather1<<<dim3(128, 25, NBB), 256, 0, stream>>>(src, x0b, W, bb0);
            else           gather2<<<dim3(128, 25, NBB), 256, 0, stream>>>(src, x0b, W, bb0);

            // tok = x0 @ Win^T (K=128) -> Abf
            gemm_bf16<<<dim3(GM, 2), 256, 0, stream>>>(x0b, Winb, Abf, nullptr, 256, 128, 0, 0, W);
            ln_bf16<<<(int)(T / 4), 256, 0, stream>>>(Abf, tnb, ln_w, ln_b);
            // fused qk (tn) + v (tok) projections, K=256
            gemm_qkv<<<dim3(GM, 6), 256, 0, stream>>>(tnb, Abf, Wqkvb, QKtok, Vtok);
            vtrans<<<dim3(W, 8), 256, 0, stream>>>(Vtok, Vt, W);
            attn_mfma<<<dim3(W, 8), 64, 0, stream>>>(QKtok, Vt, Db, W);
            // tok += ob @ attn_out_w^T  (in-place bf16 residual)
            gemm_bf16<<<dim3(GM, 2), 256, 0, stream>>>(Db, Waob, Abf, Abf, 256, 256, 0, 0, W);
            ln_bf16<<<(int)(T / 4), 256, 0, stream>>>(Abf, tnb, ffn_ln_w, ffn_ln_b);
            // hidden = relu(tn2 @ ff1^T) (N=512)
            gemm_bf16<<<dim3(GM, 4), 256, 0, stream>>>(tnb, Wff1b, hidb, nullptr, 512, 256, 1, 0, W);
            // tok += hidden @ ff2^T (K=512, in-place residual)
            gemm_bf16<<<dim3(GM, 2), 256, 0, stream>>>(hidb, Wff2b, Abf, Abf, 256, 512, 0, 0, W);
            // ot = tok @ Wout^T (N=128) -> fused scatter into xp (pixel-major)
            gemm_bf16<<<dim3(GM, 1), 256, 0, stream>>>(Abf, Woutb, xp, nullptr, 128, 256, 0, pass + 1, W);

            conv_mfma<<<dim3(8, NBB * 25), 256, 0, stream>>>(
                xp, wb, (pass == 0) ? buffer : (const float*)out, out, bb0);
        }
    }
}